// Round 9
// baseline (835.298 us; speedup 1.0000x reference)
//
#include <hip/hip_runtime.h>
#include <stdint.h>
#include <math.h>

// Problem constants: B=16, H=W=56, HW=3136, pipeline 256 -> 64 -> 64 -> 256
#define HW 3136
#define NPIX 50176  // 16*3136

// ---------------------------------------------------------------------------
// MFMA types & helpers (gfx950 v_mfma_f32_16x16x32_bf16)
// ---------------------------------------------------------------------------
typedef __attribute__((ext_vector_type(8))) short bf16x8;
typedef __attribute__((ext_vector_type(4))) float f32x4;
#define MFMA16(a, b, c) __builtin_amdgcn_mfma_f32_16x16x32_bf16(a, b, c, 0, 0, 0)

__device__ __forceinline__ unsigned short f2bf(float f) {  // RNE f32->bf16
  unsigned u = __float_as_uint(f);
  u = (u + 0x7fffu + ((u >> 16) & 1u)) >> 16;
  return (unsigned short)u;
}
__device__ __forceinline__ unsigned pk2(float a, float b) {
  return (unsigned)f2bf(a) | ((unsigned)f2bf(b) << 16);
}
__device__ __forceinline__ float bf2f(unsigned short h) {
  return __uint_as_float(((unsigned)h) << 16);
}

// ---------------------------------------------------------------------------
// threefry2x32 (Random123 / JAX-exact). ROTL = single v_alignbit via builtin.
// ---------------------------------------------------------------------------
#define ROTL32(v, r) __builtin_rotateleft32((uint32_t)(v), (r))

__host__ __device__ inline void threefry2x32(uint32_t k0, uint32_t k1,
                                             uint32_t x0, uint32_t x1,
                                             uint32_t& o0, uint32_t& o1) {
  uint32_t k2 = k0 ^ k1 ^ 0x1BD11BDAu;
  x0 += k0; x1 += k1;
  x0 += x1; x1 = ROTL32(x1, 13); x1 ^= x0;
  x0 += x1; x1 = ROTL32(x1, 15); x1 ^= x0;
  x0 += x1; x1 = ROTL32(x1, 26); x1 ^= x0;
  x0 += x1; x1 = ROTL32(x1, 6);  x1 ^= x0;
  x0 += k1; x1 += k2 + 1u;
  x0 += x1; x1 = ROTL32(x1, 17); x1 ^= x0;
  x0 += x1; x1 = ROTL32(x1, 29); x1 ^= x0;
  x0 += x1; x1 = ROTL32(x1, 16); x1 ^= x0;
  x0 += x1; x1 = ROTL32(x1, 24); x1 ^= x0;
  x0 += k2; x1 += k0 + 2u;
  x0 += x1; x1 = ROTL32(x1, 13); x1 ^= x0;
  x0 += x1; x1 = ROTL32(x1, 15); x1 ^= x0;
  x0 += x1; x1 = ROTL32(x1, 26); x1 ^= x0;
  x0 += x1; x1 = ROTL32(x1, 6);  x1 ^= x0;
  x0 += k0; x1 += k1 + 3u;
  x0 += x1; x1 = ROTL32(x1, 17); x1 ^= x0;
  x0 += x1; x1 = ROTL32(x1, 29); x1 ^= x0;
  x0 += x1; x1 = ROTL32(x1, 16); x1 ^= x0;
  x0 += x1; x1 = ROTL32(x1, 24); x1 ^= x0;
  x0 += k1; x1 += k2 + 4u;
  x0 += x1; x1 = ROTL32(x1, 13); x1 ^= x0;
  x0 += x1; x1 = ROTL32(x1, 15); x1 ^= x0;
  x0 += x1; x1 = ROTL32(x1, 26); x1 ^= x0;
  x0 += x1; x1 = ROTL32(x1, 6);  x1 ^= x0;
  x0 += k2; x1 += k0 + 5u;
  o0 = x0; o1 = x1;
}

// 5 threefry2x32 instances in lockstep (single-instr rotations, ILP=5).
#define TF5_R(r)                                            \
  _Pragma("unroll") for (int i = 0; i < 5; ++i) {           \
    x0[i] += x1[i]; x1[i] = ROTL32(x1[i], r) ^ x0[i];       \
  }
#define TF5_INJ(a, b)                                       \
  _Pragma("unroll") for (int i = 0; i < 5; ++i) {           \
    x0[i] += (a); x1[i] += (b);                             \
  }
__device__ __forceinline__ void threefry5(uint32_t k0, uint32_t k1,
    const uint32_t xa[5], const uint32_t xb[5], uint32_t oa[5], uint32_t ob[5]) {
  uint32_t k2 = k0 ^ k1 ^ 0x1BD11BDAu;
  uint32_t x0[5], x1[5];
  #pragma unroll
  for (int i = 0; i < 5; ++i) { x0[i] = xa[i] + k0; x1[i] = xb[i] + k1; }
  TF5_R(13) TF5_R(15) TF5_R(26) TF5_R(6)  TF5_INJ(k1, k2 + 1u)
  TF5_R(17) TF5_R(29) TF5_R(16) TF5_R(24) TF5_INJ(k2, k0 + 2u)
  TF5_R(13) TF5_R(15) TF5_R(26) TF5_R(6)  TF5_INJ(k0, k1 + 3u)
  TF5_R(17) TF5_R(29) TF5_R(16) TF5_R(24) TF5_INJ(k1, k2 + 4u)
  TF5_R(13) TF5_R(15) TF5_R(26) TF5_R(6)  TF5_INJ(k2, k0 + 5u)
  #pragma unroll
  for (int i = 0; i < 5; ++i) { oa[i] = x0[i]; ob[i] = x1[i]; }
}

// exp-race form: argmax(l + gumbel) == argmin( (-ln u) * exp(-l) ).
#define NLN2F -0.6931471805599453f
#define NEG2LOG2E -2.8853900817779268f
__device__ __forceinline__ float exp_draw(uint32_t bits) {
  float u = __uint_as_float((bits >> 9) | 0x3f800000u) - 1.0f;
  u = fmaxf(u, 1.17549435e-38f);
  return NLN2F * __log2f(u);   // -ln(u) >= 0
}

// ---------------------------------------------------------------------------
// sample5 body (FULL pair; fallback path): identical math to prior rounds.
// ---------------------------------------------------------------------------
template <int NT>
__device__ void sample5_body(const unsigned short* __restrict__ CS,
    float* __restrict__ acc, uint32_t key0, uint32_t key1, int BC, float scale,
    int u, unsigned* kmin, float* wsum) {
  const int v = u + (BC >> 1);
  const uint32_t sC = (uint32_t)BC * (uint32_t)HW;
  const uint32_t halfn = sC * 2u + (sC >> 1);
  const unsigned short* rowU = CS + (size_t)u * HW;
  const unsigned short* rowV = CS + (size_t)v * HW;
  const int tid = threadIdx.x;
  const int lane = tid & 63;

  if (tid < 10) { kmin[tid] = 0xFFFFFFFFu; wsum[tid] = 0.f; }

  unsigned bk[10];
  #pragma unroll
  for (int k = 0; k < 10; ++k) bk[k] = 0xFFFFFFFFu;

  const uint32_t baseU0 = (uint32_t)u * (uint32_t)HW;
  const uint32_t baseV0 = (uint32_t)v * (uint32_t)HW;
  for (int p = tid; p < HW; p += NT) {
    float wu = __builtin_amdgcn_exp2f(bf2f(rowU[p]) * NEG2LOG2E);  // exp(-2c)
    float wv = __builtin_amdgcn_exp2f(bf2f(rowV[p]) * NEG2LOG2E);
    uint32_t eU = baseU0 + (uint32_t)p;
    uint32_t eV = baseV0 + (uint32_t)p;
    uint32_t xa[5] = {eU, eU + sC, eU + 2 * sC, eV, eV + sC};
    uint32_t xb[5] = {eU + halfn, eU + sC + halfn, eU + 2 * sC + halfn,
                      eV + halfn, eV + sC + halfn};
    uint32_t oa[5], ob[5];
    threefry5(key0, key1, xa, xb, oa, ob);
    uint32_t wds[10] = {oa[0], oa[1], oa[2], ob[3], ob[4],   // u s0..s4
                        oa[3], oa[4], ob[0], ob[1], ob[2]};  // v s0..s4
    #pragma unroll
    for (int k = 0; k < 10; ++k) {
      float s = exp_draw(wds[k]) * (k < 5 ? wu : wv);
      unsigned key = (__float_as_uint(s) & 0xFFFFF000u) | (unsigned)p;
      bk[k] = bk[k] < key ? bk[k] : key;
    }
  }

  __syncthreads();  // kmin/wsum init visible
  #pragma unroll
  for (int k = 0; k < 10; ++k) {
    unsigned kv = bk[k];
    #pragma unroll
    for (int o = 32; o; o >>= 1) {
      unsigned ov = __shfl_xor(kv, o);
      kv = kv < ov ? kv : ov;
    }
    if (lane == 0) atomicMin(&kmin[k], kv);
  }
  __syncthreads();

  for (int idx = tid; idx < 1210; idx += NT) {
    int win = idx / 121, j = idx - win * 121;
    int bidx = (int)(kmin[win] & 0xFFFu);
    int py = bidx / 56, px = bidx % 56;
    int yy = py + j / 11 - 5, xx = px + j % 11 - 5;
    if (yy >= 0 && yy < 56 && xx >= 0 && xx < 56) {
      const unsigned short* row = (win < 5) ? rowU : rowV;
      atomicAdd(&wsum[win], bf2f(row[yy * 56 + xx]));
    }
  }
  __syncthreads();
  if (tid == 0) {
    float t = 0.f;
    #pragma unroll
    for (int k = 0; k < 10; ++k) t += wsum[k];
    atomicAdd(acc, t * scale);
  }
}

// standalone sampling kernel (fallback path for stages 1 and 2)
template <int NT>
__global__ __launch_bounds__(NT) void sample5_k(const unsigned short* __restrict__ CS,
    float* __restrict__ acc, uint32_t key0, uint32_t key1, int BC, float scale) {
  __shared__ unsigned kmin[10];
  __shared__ float wsum[10];
  sample5_body<NT>(CS, acc, key0, key1, BC, scale, blockIdx.x, kmin, wsum);
}

// ---------------------------------------------------------------------------
// sample5 HALF-pair (mega v7): this block processes pixels
// [half*1568, (half+1)*1568) of pair u. Winner combine across the two
// half-blocks via device-scope atomicMin into gk[10]; the SECOND block to
// finish (elected by pairDone counter) reads the combined minima and does
// the 11x11 window sums + acc add. The argmin key embeds the global pixel
// index, so the split is bit-exact vs the full-pair version.
// ---------------------------------------------------------------------------
template <int NT>
__device__ void sample5_half(const unsigned short* __restrict__ CS,
    float* __restrict__ acc, uint32_t key0, uint32_t key1, int BC, float scale,
    int u, int half, unsigned* __restrict__ gk, unsigned* __restrict__ pd,
    unsigned* kmin, float* wsum) {
  const int v = u + (BC >> 1);
  const uint32_t sC = (uint32_t)BC * (uint32_t)HW;
  const uint32_t halfn = sC * 2u + (sC >> 1);
  const unsigned short* rowU = CS + (size_t)u * HW;
  const unsigned short* rowV = CS + (size_t)v * HW;
  const int tid = threadIdx.x;
  const int lane = tid & 63;

  if (tid < 10) { kmin[tid] = 0xFFFFFFFFu; wsum[tid] = 0.f; }

  unsigned bk[10];
  #pragma unroll
  for (int k = 0; k < 10; ++k) bk[k] = 0xFFFFFFFFu;

  const uint32_t baseU0 = (uint32_t)u * (uint32_t)HW;
  const uint32_t baseV0 = (uint32_t)v * (uint32_t)HW;
  const int pEnd = (half + 1) * (HW / 2);
  for (int p = half * (HW / 2) + tid; p < pEnd; p += NT) {
    float wu = __builtin_amdgcn_exp2f(bf2f(rowU[p]) * NEG2LOG2E);  // exp(-2c)
    float wv = __builtin_amdgcn_exp2f(bf2f(rowV[p]) * NEG2LOG2E);
    uint32_t eU = baseU0 + (uint32_t)p;
    uint32_t eV = baseV0 + (uint32_t)p;
    uint32_t xa[5] = {eU, eU + sC, eU + 2 * sC, eV, eV + sC};
    uint32_t xb[5] = {eU + halfn, eU + sC + halfn, eU + 2 * sC + halfn,
                      eV + halfn, eV + sC + halfn};
    uint32_t oa[5], ob[5];
    threefry5(key0, key1, xa, xb, oa, ob);
    uint32_t wds[10] = {oa[0], oa[1], oa[2], ob[3], ob[4],   // u s0..s4
                        oa[3], oa[4], ob[0], ob[1], ob[2]};  // v s0..s4
    #pragma unroll
    for (int k = 0; k < 10; ++k) {
      float s = exp_draw(wds[k]) * (k < 5 ? wu : wv);
      unsigned key = (__float_as_uint(s) & 0xFFFFF000u) | (unsigned)p;
      bk[k] = bk[k] < key ? bk[k] : key;
    }
  }

  __syncthreads();  // kmin/wsum init visible
  #pragma unroll
  for (int k = 0; k < 10; ++k) {
    unsigned kv = bk[k];
    #pragma unroll
    for (int o = 32; o; o >>= 1) {
      unsigned ov = __shfl_xor(kv, o);
      kv = kv < ov ? kv : ov;
    }
    if (lane == 0) atomicMin(&kmin[k], kv);
  }
  __syncthreads();

  // push block minima to the pair's global slots (device-scope atomics)
  if (tid < 10) atomicMin(&gk[tid], kmin[tid]);
  __shared__ unsigned prevS;
  if (tid == 0) { __threadfence(); prevS = atomicAdd(pd, 1u); }
  __syncthreads();
  if (prevS == 1u) {  // second arriver: both halves' minima are visible
    if (tid < 10) kmin[tid] = atomicMin(&gk[tid], 0xFFFFFFFFu);  // atomic read
    __syncthreads();
    for (int idx = tid; idx < 1210; idx += NT) {
      int win = idx / 121, j = idx - win * 121;
      int bidx = (int)(kmin[win] & 0xFFFu);
      int py = bidx / 56, px = bidx % 56;
      int yy = py + j / 11 - 5, xx = px + j % 11 - 5;
      if (yy >= 0 && yy < 56 && xx >= 0 && xx < 56) {
        const unsigned short* row = (win < 5) ? rowU : rowV;
        atomicAdd(&wsum[win], bf2f(row[yy * 56 + xx]));
      }
    }
    __syncthreads();
    if (tid == 0) {
      float t = 0.f;
      #pragma unroll
      for (int k = 0; k < 10; ++k) t += wsum[k];
      atomicAdd(acc, t * scale);
    }
  }
}

// ---------------------------------------------------------------------------
// MEGA kernel v7: half-pair blocks for constant 32-sampling-waves/CU.
// Round-8 lesson (3-point curve): sampling efficiency vs resident sampling
// waves/CU = {32w: 89.6%, 24w: 76%, 16w: ~60%}. Only full residency is
// efficient. 3072 pairs / 2048 slots = 1.5 forces a sub-residency tail --
// so SPLIT each pair into two half-pair blocks: 6144 blocks = exactly 3
// full-residency cohorts; dispatcher backfill keeps 8 blocks/CU sampling
// until the final drain. Finals (~6 chunks each) on blocks g<2048 only:
// one ~6us burst at t~55 followed by backfilled sampling; no end burst.
// Global pair list: [0,512) stage1 (CS1, A0/A1, BC=1024)
//                   [512,1024) stage2 (CS2, A2/B0, BC=1024)
//                   [1024,3072) stage3 (CS3, B1/B2, BC=4096)
// __launch_bounds__(256,8): 256-thread shape reliably compiles to ~32 VGPR.
// ---------------------------------------------------------------------------
__device__ __forceinline__ void final_chunk(int chunk,
    const unsigned short* __restrict__ Y3, const float* __restrict__ X,
    const float* __restrict__ sc, const float* __restrict__ sh,
    float* __restrict__ out) {
  size_t i = ((size_t)chunk * 256 + threadIdx.x) * 4;
  int c = (int)((i / HW) % 256);
  float a = sc[c], d = sh[c];
  uint2 yd = *(const uint2*)&Y3[i];
  float4 xv = *(const float4*)&X[i];
  float4 r;
  r.x = fmaxf(0.f, fmaf(bf2f((unsigned short)(yd.x & 0xffff)), a, d) + xv.x);
  r.y = fmaxf(0.f, fmaf(bf2f((unsigned short)(yd.x >> 16)),    a, d) + xv.y);
  r.z = fmaxf(0.f, fmaf(bf2f((unsigned short)(yd.y & 0xffff)), a, d) + xv.z);
  r.w = fmaxf(0.f, fmaf(bf2f((unsigned short)(yd.y >> 16)),    a, d) + xv.w);
  *(float4*)&out[i] = r;
}

__global__ __launch_bounds__(256, 8) void mega_k(
    const unsigned short* __restrict__ CS1, const unsigned short* __restrict__ CS2,
    const unsigned short* __restrict__ CS3,
    const unsigned short* __restrict__ Y3, const float* __restrict__ X,
    const float* __restrict__ sc, const float* __restrict__ sh,
    float* __restrict__ out, float* __restrict__ accp, unsigned* __restrict__ done,
    unsigned* __restrict__ gkmin, unsigned* __restrict__ pairDone,
    uint32_t A0, uint32_t A1, uint32_t A2, uint32_t B0, uint32_t B1, uint32_t B2,
    float s64, float s256, int pairStart, int finalCnt) {
  __shared__ unsigned kmin[10];
  __shared__ float wsum[10];
  const int g = blockIdx.x;
  const int lp = g >> 1, half = g & 1;
  const int pi = pairStart + lp;
  unsigned* gk = gkmin + (size_t)lp * 10;
  unsigned* pd = pairDone + lp;
  if (pi < 512)
    sample5_half<256>(CS1, accp, A0, A1, 1024, s64, pi, half, gk, pd, kmin, wsum);
  else if (pi < 1024)
    sample5_half<256>(CS2, accp, A2, B0, 1024, s64, pi - 512, half, gk, pd, kmin, wsum);
  else
    sample5_half<256>(CS3, accp, B1, B2, 4096, s256, pi - 1024, half, gk, pd, kmin, wsum);
  if (g < finalCnt)
    for (int cc = g; cc < 12544; cc += finalCnt)
      final_chunk(cc, Y3, X, sc, sh, out);
  // last block writes the scalar tail (device-scope; all acc adds fenced)
  if (threadIdx.x == 0) {
    __threadfence();
    unsigned prev = atomicAdd(done, 1u);
    if (prev == (unsigned)(gridDim.x - 1)) {
      float v = atomicAdd(accp, 0.f);  // atomic read through L2
      out[12845056] = v;
    }
  }
}

// ---------------------------------------------------------------------------
// weight prep: invwn[384] (1/(||w||+eps)) + bf16 weight conversion.
// ---------------------------------------------------------------------------
__global__ void wprep_k(const float* __restrict__ w1, const float* __restrict__ w2,
                        const float* __restrict__ w3, float* __restrict__ invwn,
                        unsigned short* __restrict__ W1b, unsigned short* __restrict__ W2tb,
                        unsigned short* __restrict__ W3b) {
  int i = blockIdx.x * 256 + threadIdx.x;
  if (i < 16384) {
    W1b[i] = f2bf(w1[i]);
  } else if (i < 53248) {
    int o = i - 16384;
    int co = o / 576, r = o % 576, tap = r >> 6, ci = r & 63;
    W2tb[o] = f2bf(w2[co * 576 + ci * 9 + tap]);
  } else if (i < 69632) {
    int o = i - 53248;
    W3b[o] = f2bf(w3[o]);
  } else {
    int t = i - 69632;
    if (t < 64) {
      float s = 0.f;
      for (int k = 0; k < 256; k++) { float v = w1[t * 256 + k]; s = fmaf(v, v, s); }
      invwn[t] = 1.0f / (sqrtf(s) + 1e-6f);
    } else if (t < 128) {
      int c = t - 64; float s = 0.f;
      for (int k = 0; k < 576; k++) { float v = w2[c * 576 + k]; s = fmaf(v, v, s); }
      invwn[t] = 1.0f / (sqrtf(s) + 1e-6f);
    } else if (t < 384) {
      int c = t - 128; float s = 0.f;
      for (int k = 0; k < 64; k++) { float v = w3[c * 64 + k]; s = fmaf(v, v, s); }
      invwn[t] = 1.0f / (sqrtf(s) + 1e-6f);
    }
  }
}

// ---------------------------------------------------------------------------
// BN finalize from per-block partials, channel-major [co][nblk].
// ---------------------------------------------------------------------------
__global__ __launch_bounds__(256) void bn_fin(const float* __restrict__ Sp,
    const float* __restrict__ Qp, const float* __restrict__ g,
    const float* __restrict__ b, float* __restrict__ sc, float* __restrict__ sh,
    int nblk) {
  const int c = blockIdx.x, tid = threadIdx.x;
  const float* rs = Sp + (size_t)c * nblk;
  const float* rq = Qp + (size_t)c * nblk;
  float s = 0.f, q = 0.f;
  for (int i = tid; i < nblk; i += 256) { s += rs[i]; q += rq[i]; }
  #pragma unroll
  for (int o = 32; o; o >>= 1) { s += __shfl_xor(s, o); q += __shfl_xor(q, o); }
  __shared__ float S[4], Q[4];
  int lane = tid & 63, wave = tid >> 6;
  if (lane == 0) { S[wave] = s; Q[wave] = q; }
  __syncthreads();
  if (tid == 0) {
    float st = S[0] + S[1] + S[2] + S[3];
    float qt = Q[0] + Q[1] + Q[2] + Q[3];
    float mean = st * (1.0f / (float)NPIX);
    float var = qt * (1.0f / (float)NPIX) - mean * mean;  // biased, jnp.var
    float sv = g[c] / sqrtf(var + 1e-5f);
    sc[c] = sv; sh[c] = b[c] - mean * sv;
  }
}

// ---------------------------------------------------------------------------
// conv1: 1x1 256->64 MFMA. Block = 64px x 64co, grid (49,16).
// ---------------------------------------------------------------------------
__global__ __launch_bounds__(256) void conv1_mfma(
    const float* __restrict__ X, const unsigned short* __restrict__ Wb,
    const float* __restrict__ invwn, unsigned short* __restrict__ Y1,
    unsigned short* __restrict__ CS, float* __restrict__ Sp, float* __restrict__ Qp) {
#define ST1 264
#define NB1 784
  __shared__ __align__(16) unsigned short bq[64 * ST1];
  __shared__ float sqp[4][64];
  __shared__ float ixn[64];
  const int p0 = blockIdx.x * 64, b = blockIdx.y;
  const int bid = b * 49 + blockIdx.x;
  const int tid = threadIdx.x;
  const int lane = tid & 63, wave = tid >> 6;
  const int m = lane & 15, quad = lane >> 4;
  const int co0 = wave * 16;
  const float* Xb = X + (size_t)b * 256 * HW + p0;

  bf16x8 afr[8];
  const unsigned short* wrow = Wb + (co0 + m) * 256 + quad * 8;
  #pragma unroll
  for (int k = 0; k < 8; ++k) afr[k] = *(const bf16x8*)(wrow + k * 32);

  {
    const int px = tid & 63, rg = tid >> 6;
    float sq = 0.f;
    #pragma unroll
    for (int it = 0; it < 16; ++it) {
      int ci = rg * 64 + it * 4;
      float v0 = Xb[(size_t)(ci + 0) * HW + px];
      float v1 = Xb[(size_t)(ci + 1) * HW + px];
      float v2 = Xb[(size_t)(ci + 2) * HW + px];
      float v3 = Xb[(size_t)(ci + 3) * HW + px];
      sq += v0 * v0 + v1 * v1 + v2 * v2 + v3 * v3;
      *(uint2*)&bq[px * ST1 + ci] = make_uint2(pk2(v0, v1), pk2(v2, v3));
    }
    sqp[rg][px] = sq;
  }
  __syncthreads();
  if (tid < 64)
    ixn[tid] = 1.0f / (sqrtf(sqp[0][tid] + sqp[1][tid] + sqp[2][tid] + sqp[3][tid]) + 1e-6f);
  __syncthreads();

  f32x4 acc[4];
  #pragma unroll
  for (int nt = 0; nt < 4; ++nt) acc[nt] = (f32x4)0.f;
  #pragma unroll
  for (int nt = 0; nt < 4; ++nt) {
    const unsigned short* brow = &bq[(nt * 16 + m) * ST1 + quad * 8];
    #pragma unroll
    for (int k = 0; k < 8; ++k) {
      bf16x8 bfrag = *(const bf16x8*)(brow + k * 32);
      acc[nt] = MFMA16(afr[k], bfrag, acc[nt]);
    }
  }

  float s[4] = {0, 0, 0, 0}, q[4] = {0, 0, 0, 0};
  #pragma unroll
  for (int nt = 0; nt < 4; ++nt) {
    int px = nt * 16 + m;
    size_t bp = (size_t)b * HW + p0 + px;
    float ix = ixn[px];
    *(uint2*)&Y1[bp * 64 + co0 + quad * 4] =
        make_uint2(pk2(acc[nt][0], acc[nt][1]), pk2(acc[nt][2], acc[nt][3]));
    #pragma unroll
    for (int r = 0; r < 4; ++r) {
      int co = co0 + quad * 4 + r;
      float v = acc[nt][r];
      CS[((size_t)b * 64 + co) * HW + p0 + px] = f2bf(v * invwn[co] * ix);
      s[r] += v; q[r] = fmaf(v, v, q[r]);
    }
  }
  #pragma unroll
  for (int r = 0; r < 4; ++r) {
    float ss = s[r], qq = q[r];
    #pragma unroll
    for (int o = 8; o; o >>= 1) { ss += __shfl_xor(ss, o); qq += __shfl_xor(qq, o); }
    if (m == 0) {
      int co = co0 + quad * 4 + r;
      Sp[(size_t)co * NB1 + bid] = ss; Qp[(size_t)co * NB1 + bid] = qq;
    }
  }
#undef NB1
#undef ST1
}

// ---------------------------------------------------------------------------
// conv2: 3x3 64->64 pad1, implicit-GEMM MFMA. grid (56,16). CS bf16.
// FUSED x_norm: the staged ts tile IS relu(bn1(y1)) (zero-padded), which is
// exactly what part(pixel) = sum_ci t1^2 needs for rows h-1..h+1. Compute
// spart[3][56] from ts, box-sum 3x3 in the epilogue.
// ---------------------------------------------------------------------------
__global__ __launch_bounds__(256) void conv2_mfma(
    const unsigned short* __restrict__ Y1, const unsigned short* __restrict__ W2tb,
    const float* __restrict__ invwn,
    const float* __restrict__ sc1, const float* __restrict__ sh1,
    unsigned short* __restrict__ Y2, unsigned short* __restrict__ CS,
    float* __restrict__ Sp, float* __restrict__ Qp) {
#define STW 72
#define NB2 896
  __shared__ __align__(16) unsigned short ts[3 * 66 * STW];
  __shared__ float scl[64], shl[64];
  __shared__ float spart[3 * 56];
  const int h = blockIdx.x, b = blockIdx.y;
  const int bid = b * 56 + h;
  const int tid = threadIdx.x;
  const int lane = tid & 63, wave = tid >> 6;
  const int m = lane & 15, quad = lane >> 4;
  const int co0 = wave * 16;
  if (tid < 64) { scl[tid] = sc1[tid]; shl[tid] = sh1[tid]; }

  bf16x8 afr[18];
  #pragma unroll
  for (int ks = 0; ks < 18; ++ks)
    afr[ks] = *(const bf16x8*)(W2tb + (co0 + m) * 576 + ks * 32 + quad * 8);
  __syncthreads();

  for (int l = tid; l < 6336; l += 256) {  // 3 rows x 66 cols x 32 ci-pairs
    int cp = l & 31, cc = (l >> 5) % 66, dy = l / 2112;
    int yy = h - 1 + dy, xx = cc - 1;
    unsigned pkv = 0u;
    if (yy >= 0 && yy < 56 && xx >= 0 && xx < 56) {
      unsigned d = *(const unsigned*)&Y1[((size_t)b * HW + yy * 56 + xx) * 64 + cp * 2];
      float v0 = bf2f((unsigned short)(d & 0xffff));
      float v1 = bf2f((unsigned short)(d >> 16));
      v0 = fmaxf(0.f, fmaf(v0, scl[cp * 2], shl[cp * 2]));
      v1 = fmaxf(0.f, fmaf(v1, scl[cp * 2 + 1], shl[cp * 2 + 1]));
      pkv = pk2(v0, v1);
    }
    *(unsigned*)&ts[(dy * 66 + cc) * STW + cp * 2] = pkv;
  }
  __syncthreads();

  // spart[dy][x] = sum_ci ts[dy][x+1][ci]^2
  if (tid < 168) {
    int dy = tid / 56, x = tid - dy * 56;
    const unsigned* row = (const unsigned*)&ts[(dy * 66 + x + 1) * STW];
    float s = 0.f;
    #pragma unroll
    for (int j = 0; j < 32; ++j) {
      unsigned d = row[j];
      float v0 = bf2f((unsigned short)(d & 0xffff));
      float v1 = bf2f((unsigned short)(d >> 16));
      s = fmaf(v0, v0, s); s = fmaf(v1, v1, s);
    }
    spart[tid] = s;
  }
  __syncthreads();

  f32x4 acc[4];
  #pragma unroll
  for (int nt = 0; nt < 4; ++nt) acc[nt] = (f32x4)0.f;
  #pragma unroll
  for (int nt = 0; nt < 4; ++nt) {
    #pragma unroll
    for (int ks = 0; ks < 18; ++ks) {
      int tap = ks >> 1, half = ks & 1;
      int dy = tap / 3, dx = tap % 3;
      bf16x8 bfrag = *(const bf16x8*)&ts[(dy * 66 + nt * 16 + m + dx) * STW + half * 32 + quad * 8];
      acc[nt] = MFMA16(afr[ks], bfrag, acc[nt]);
    }
  }

  float s[4] = {0, 0, 0, 0}, q[4] = {0, 0, 0, 0};
  #pragma unroll
  for (int nt = 0; nt < 4; ++nt) {
    int px = nt * 16 + m;
    bool valid = px < 56;
    int pix = h * 56 + px;
    if (valid) {
      float tot = 0.f;
      #pragma unroll
      for (int dy = 0; dy < 3; ++dy) {
        #pragma unroll
        for (int dx = -1; dx <= 1; ++dx) {
          int xx = px + dx;
          if (xx >= 0 && xx < 56) tot += spart[dy * 56 + xx];
        }
      }
      float ix = 1.0f / (sqrtf(tot) + 1e-6f);
      size_t bp = (size_t)b * HW + pix;
      *(uint2*)&Y2[bp * 64 + co0 + quad * 4] =
          make_uint2(pk2(acc[nt][0], acc[nt][1]), pk2(acc[nt][2], acc[nt][3]));
      #pragma unroll
      for (int r = 0; r < 4; ++r) {
        int co = co0 + quad * 4 + r;
        CS[((size_t)b * 64 + co) * HW + pix] = f2bf(acc[nt][r] * invwn[co] * ix);
      }
    }
    #pragma unroll
    for (int r = 0; r < 4; ++r) {
      float v = valid ? acc[nt][r] : 0.f;
      s[r] += v; q[r] = fmaf(v, v, q[r]);
    }
  }
  #pragma unroll
  for (int r = 0; r < 4; ++r) {
    float ss = s[r], qq = q[r];
    #pragma unroll
    for (int o = 8; o; o >>= 1) { ss += __shfl_xor(ss, o); qq += __shfl_xor(qq, o); }
    if (m == 0) {
      int co = co0 + quad * 4 + r;
      Sp[(size_t)co * NB2 + bid] = ss; Qp[(size_t)co * NB2 + bid] = qq;
    }
  }
#undef NB2
#undef STW
}

// ---------------------------------------------------------------------------
// conv3: 1x1 64->256 MFMA. grid (49,16). Outputs y3 bf16 + cos3 bf16.
// ---------------------------------------------------------------------------
__global__ __launch_bounds__(256) void conv3_mfma(
    const unsigned short* __restrict__ Y2, const unsigned short* __restrict__ W3b,
    const float* __restrict__ invwn,
    const float* __restrict__ sc2, const float* __restrict__ sh2,
    unsigned short* __restrict__ Y3, unsigned short* __restrict__ CS,
    float* __restrict__ Sp, float* __restrict__ Qp) {
#define ST3 72
#define NB3 784
  __shared__ __align__(16) unsigned short bq[64 * ST3];
  __shared__ float scl[64], shl[64], sqp[4][64], ixn[64];
  const int p0 = blockIdx.x * 64, b = blockIdx.y;
  const int bid = b * 49 + blockIdx.x;
  const int tid = threadIdx.x;
  const int lane = tid & 63, wave = tid >> 6;
  const int m = lane & 15, quad = lane >> 4;
  const int co0 = wave * 64;
  if (tid < 64) { scl[tid] = sc2[tid]; shl[tid] = sh2[tid]; }

  bf16x8 afr[4][2];
  #pragma unroll
  for (int mt = 0; mt < 4; ++mt)
    #pragma unroll
    for (int k = 0; k < 2; ++k)
      afr[mt][k] = *(const bf16x8*)(W3b + (co0 + mt * 16 + m) * 64 + k * 32 + quad * 8);
  __syncthreads();

  {
    const int cp = tid & 31, pxg = tid >> 5;
    #pragma unroll
    for (int it = 0; it < 8; ++it) {
      int px = pxg * 8 + it;
      unsigned d = *(const unsigned*)&Y2[((size_t)b * HW + p0 + px) * 64 + cp * 2];
      float v0 = bf2f((unsigned short)(d & 0xffff));
      float v1 = bf2f((unsigned short)(d >> 16));
      v0 = fmaxf(0.f, fmaf(v0, scl[cp * 2], shl[cp * 2]));
      v1 = fmaxf(0.f, fmaf(v1, scl[cp * 2 + 1], shl[cp * 2 + 1]));
      *(unsigned*)&bq[px * ST3 + cp * 2] = pk2(v0, v1);
    }
  }
  __syncthreads();
  {
    const int px = tid & 63, hh = tid >> 6;
    const unsigned short* row = &bq[px * ST3 + hh * 16];
    float sq = 0.f;
    #pragma unroll
    for (int e = 0; e < 16; ++e) { float v = bf2f(row[e]); sq = fmaf(v, v, sq); }
    sqp[hh][px] = sq;
  }
  __syncthreads();
  if (tid < 64)
    ixn[tid] = 1.0f / (sqrtf(sqp[0][tid] + sqp[1][tid] + sqp[2][tid] + sqp[3][tid]) + 1e-6f);
  __syncthreads();

  f32x4 acc[4][4];
  #pragma unroll
  for (int mt = 0; mt < 4; ++mt)
    #pragma unroll
    for (int nt = 0; nt < 4; ++nt) acc[mt][nt] = (f32x4)0.f;
  #pragma unroll
  for (int nt = 0; nt < 4; ++nt) {
    const unsigned short* brow = &bq[(nt * 16 + m) * ST3 + quad * 8];
    bf16x8 b0 = *(const bf16x8*)(brow);
    bf16x8 b1 = *(const bf16x8*)(brow + 32);
    #pragma unroll
    for (int mt = 0; mt < 4; ++mt) {
      acc[mt][nt] = MFMA16(afr[mt][0], b0, acc[mt][nt]);
      acc[mt][nt] = MFMA16(afr[mt][1], b1, acc[mt][nt]);
    }
  }

  #pragma unroll
  for (int mt = 0; mt < 4; ++mt) {
    float s[4] = {0, 0, 0, 0}, q[4] = {0, 0, 0, 0};
    #pragma unroll
    for (int nt = 0; nt < 4; ++nt) {
      int px = nt * 16 + m;
      float ix = ixn[px];
      #pragma unroll
      for (int r = 0; r < 4; ++r) {
        int co = co0 + mt * 16 + quad * 4 + r;
        float v = acc[mt][nt][r];
        size_t off = ((size_t)b * 256 + co) * HW + p0 + px;
        Y3[off] = f2bf(v);
        CS[off] = f2bf(v * invwn[co] * ix);
        s[r] += v; q[r] = fmaf(v, v, q[r]);
      }
    }
    #pragma unroll
    for (int r = 0; r < 4; ++r) {
      float ss = s[r], qq = q[r];
      #pragma unroll
      for (int o = 8; o; o >>= 1) { ss += __shfl_xor(ss, o); qq += __shfl_xor(qq, o); }
      if (m == 0) {
        int co = co0 + mt * 16 + quad * 4 + r;
        Sp[(size_t)co * NB3 + bid] = ss; Qp[(size_t)co * NB3 + bid] = qq;
      }
    }
  }
#undef NB3
#undef ST3
}

// ---------------------------------------------------------------------------
extern "C" void kernel_launch(void* const* d_in, const int* in_sizes, int n_in,
                              void* d_out, int out_size, void* d_ws, size_t ws_size,
                              hipStream_t stream) {
  (void)in_sizes; (void)n_in; (void)out_size;
  const float* x  = (const float*)d_in[0];
  const float* w1 = (const float*)d_in[1];
  const float* w2 = (const float*)d_in[2];
  const float* w3 = (const float*)d_in[3];
  const float* g1 = (const float*)d_in[4];
  const float* b1 = (const float*)d_in[5];
  const float* g2 = (const float*)d_in[6];
  const float* b2 = (const float*)d_in[7];
  const float* g3 = (const float*)d_in[8];
  const float* b3 = (const float*)d_in[9];
  float* out = (float*)d_out;
  float* ws = (float*)d_ws;

  // workspace layout (float units; bf16 buffers use elems/2 float units)
  size_t o = 0;
  unsigned short* y3b  = (unsigned short*)(ws + o); o += 6422528;  // 12845056 bf16
  unsigned short* cos3 = (unsigned short*)(ws + o); o += 6422528;  // 12845056 bf16
  unsigned short* CSb  = (unsigned short*)(ws + o); o += 1605632;  // 3211264 bf16
  unsigned short* y1b  = (unsigned short*)(ws + o); o += 1605632;  // 3211264 bf16
  unsigned short* y2b  = (unsigned short*)(ws + o); o += 1605632;  // 3211264 bf16
  unsigned short* W1b  = (unsigned short*)(ws + o); o += 8192;     // 16384 bf16
  unsigned short* W2tb = (unsigned short*)(ws + o); o += 18432;    // 36864 bf16
  unsigned short* W3b  = (unsigned short*)(ws + o); o += 8192;     // 16384 bf16
  float* invwn = ws + o; o += 384;
  float* Sp1 = ws + o; o += 64 * 784;   float* Qp1 = ws + o; o += 64 * 784;
  float* Sp2 = ws + o; o += 64 * 896;   float* Qp2 = ws + o; o += 64 * 896;
  float* Sp3 = ws + o; o += 256 * 784;  float* Qp3 = ws + o; o += 256 * 784;
  // zero-init group: acc, done, pairDone[3072] (one memset)
  float* acc = ws + o; o += 1;
  unsigned* done = (unsigned*)(ws + o); o += 1;
  unsigned* pairDone = (unsigned*)(ws + o); o += 3072;
  // 0xFF-init group: gkmin[3072][10]
  unsigned* gkmin = (unsigned*)(ws + o); o += 30720;
  float* sc1 = ws + o; o += 64;  float* sh1 = ws + o; o += 64;
  float* sc2 = ws + o; o += 64;  float* sh2 = ws + o; o += 64;
  float* sc3 = ws + o; o += 256; float* sh3 = ws + o; o += 256;

  // Separate conv2-cosine buffer so stage-1/2 sampling can be deferred into
  // the mega kernel (CSb must survive conv2). Guarded by ws_size.
  const bool big = ws_size >= (o + 1605632) * sizeof(float);
  unsigned short* CS2b = big ? (unsigned short*)(ws + o) : CSb;

  hipMemsetAsync(acc, 0, (2 + 3072) * sizeof(float), stream);       // acc,done,pairDone
  hipMemsetAsync(gkmin, 0xFF, 30720 * sizeof(unsigned), stream);    // gkmin

  // JAX: k0,k1,k2 = split(key(42), 3); (Ai,Bi) = threefry2x32((0,42),(i,i+3))
  uint32_t A0, B0, A1, B1, A2, B2;
  threefry2x32(0u, 42u, 0u, 3u, A0, B0);
  threefry2x32(0u, 42u, 1u, 4u, A1, B1);
  threefry2x32(0u, 42u, 2u, 5u, A2, B2);

  const float scale64  = 1.0f / (121.0f * 5.0f * 1024.0f);
  const float scale256 = 1.0f / (121.0f * 5.0f * 4096.0f);

  wprep_k<<<274, 256, 0, stream>>>(w1, w2, w3, invwn, W1b, W2tb, W3b);

  // conv pipeline (serial deps: conv1 -> bn1 -> conv2 -> bn2 -> conv3 -> bn3)
  conv1_mfma<<<dim3(49, 16), 256, 0, stream>>>(x, W1b, invwn, y1b, CSb, Sp1, Qp1);
  bn_fin<<<64, 256, 0, stream>>>(Sp1, Qp1, g1, b1, sc1, sh1, 784);
  if (!big)  // fallback: must sample CSb before conv2 overwrites it
    sample5_k<512><<<512, 512, 0, stream>>>(CSb, acc, A0, A1, 1024, scale64);
  conv2_mfma<<<dim3(56, 16), 256, 0, stream>>>(
      y1b, W2tb, invwn + 64, sc1, sh1, y2b, CS2b, Sp2, Qp2);
  bn_fin<<<64, 256, 0, stream>>>(Sp2, Qp2, g2, b2, sc2, sh2, 896);
  if (!big)
    sample5_k<512><<<512, 512, 0, stream>>>(CS2b, acc, A2, B0, 1024, scale64);
  conv3_mfma<<<dim3(49, 16), 256, 0, stream>>>(
      y2b, W3b, invwn + 128, sc2, sh2, y3b, cos3, Sp3, Qp3);
  bn_fin<<<256, 256, 0, stream>>>(Sp3, Qp3, g3, b3, sc3, sh3, 784);

  // MEGA v7: half-pair blocks -> constant 8 sampling blocks/CU (the measured
  // 89.6%-VALUBusy regime) until the final drain. Finals on g<2048 only.
  // big:      6144 half-blocks (all 3072 pairs)
  // fallback: 4096 half-blocks (stage-3's 2048 pairs; s1/s2 sampled above)
  if (big) {
    mega_k<<<6144, 256, 0, stream>>>(
        CSb, CS2b, cos3, y3b, x, sc3, sh3, out, acc, done, gkmin, pairDone,
        A0, A1, A2, B0, B1, B2, scale64, scale256,
        /*pairStart=*/0, /*finalCnt=*/2048);
  } else {
    mega_k<<<4096, 256, 0, stream>>>(
        CSb, CS2b, cos3, y3b, x, sc3, sh3, out, acc, done, gkmin, pairDone,
        A0, A1, A2, B0, B1, B2, scale64, scale256,
        /*pairStart=*/1024, /*finalCnt=*/2048);
  }
}

// Round 10
// 397.883 us; speedup vs baseline: 2.0994x; 2.0994x over previous
//
#include <hip/hip_runtime.h>
#include <stdint.h>
#include <math.h>

// Problem constants: B=16, H=W=56, HW=3136, pipeline 256 -> 64 -> 64 -> 256
#define HW 3136
#define NPIX 50176  // 16*3136

// ---------------------------------------------------------------------------
// MFMA types & helpers (gfx950 v_mfma_f32_16x16x32_bf16)
// ---------------------------------------------------------------------------
typedef __attribute__((ext_vector_type(8))) short bf16x8;
typedef __attribute__((ext_vector_type(4))) float f32x4;
#define MFMA16(a, b, c) __builtin_amdgcn_mfma_f32_16x16x32_bf16(a, b, c, 0, 0, 0)

__device__ __forceinline__ unsigned short f2bf(float f) {  // RNE f32->bf16
  unsigned u = __float_as_uint(f);
  u = (u + 0x7fffu + ((u >> 16) & 1u)) >> 16;
  return (unsigned short)u;
}
__device__ __forceinline__ unsigned pk2(float a, float b) {
  return (unsigned)f2bf(a) | ((unsigned)f2bf(b) << 16);
}
__device__ __forceinline__ float bf2f(unsigned short h) {
  return __uint_as_float(((unsigned)h) << 16);
}

// ---------------------------------------------------------------------------
// threefry2x32 (Random123 / JAX-exact). ROTL = single v_alignbit via builtin.
// ---------------------------------------------------------------------------
#define ROTL32(v, r) __builtin_rotateleft32((uint32_t)(v), (r))

__host__ __device__ inline void threefry2x32(uint32_t k0, uint32_t k1,
                                             uint32_t x0, uint32_t x1,
                                             uint32_t& o0, uint32_t& o1) {
  uint32_t k2 = k0 ^ k1 ^ 0x1BD11BDAu;
  x0 += k0; x1 += k1;
  x0 += x1; x1 = ROTL32(x1, 13); x1 ^= x0;
  x0 += x1; x1 = ROTL32(x1, 15); x1 ^= x0;
  x0 += x1; x1 = ROTL32(x1, 26); x1 ^= x0;
  x0 += x1; x1 = ROTL32(x1, 6);  x1 ^= x0;
  x0 += k1; x1 += k2 + 1u;
  x0 += x1; x1 = ROTL32(x1, 17); x1 ^= x0;
  x0 += x1; x1 = ROTL32(x1, 29); x1 ^= x0;
  x0 += x1; x1 = ROTL32(x1, 16); x1 ^= x0;
  x0 += x1; x1 = ROTL32(x1, 24); x1 ^= x0;
  x0 += k2; x1 += k0 + 2u;
  x0 += x1; x1 = ROTL32(x1, 13); x1 ^= x0;
  x0 += x1; x1 = ROTL32(x1, 15); x1 ^= x0;
  x0 += x1; x1 = ROTL32(x1, 26); x1 ^= x0;
  x0 += x1; x1 = ROTL32(x1, 6);  x1 ^= x0;
  x0 += k0; x1 += k1 + 3u;
  x0 += x1; x1 = ROTL32(x1, 17); x1 ^= x0;
  x0 += x1; x1 = ROTL32(x1, 29); x1 ^= x0;
  x0 += x1; x1 = ROTL32(x1, 16); x1 ^= x0;
  x0 += x1; x1 = ROTL32(x1, 24); x1 ^= x0;
  x0 += k1; x1 += k2 + 4u;
  x0 += x1; x1 = ROTL32(x1, 13); x1 ^= x0;
  x0 += x1; x1 = ROTL32(x1, 15); x1 ^= x0;
  x0 += x1; x1 = ROTL32(x1, 26); x1 ^= x0;
  x0 += x1; x1 = ROTL32(x1, 6);  x1 ^= x0;
  x0 += k2; x1 += k0 + 5u;
  o0 = x0; o1 = x1;
}

// 5 threefry2x32 instances in lockstep (single-instr rotations, ILP=5).
#define TF5_R(r)                                            \
  _Pragma("unroll") for (int i = 0; i < 5; ++i) {           \
    x0[i] += x1[i]; x1[i] = ROTL32(x1[i], r) ^ x0[i];       \
  }
#define TF5_INJ(a, b)                                       \
  _Pragma("unroll") for (int i = 0; i < 5; ++i) {           \
    x0[i] += (a); x1[i] += (b);                             \
  }
__device__ __forceinline__ void threefry5(uint32_t k0, uint32_t k1,
    const uint32_t xa[5], const uint32_t xb[5], uint32_t oa[5], uint32_t ob[5]) {
  uint32_t k2 = k0 ^ k1 ^ 0x1BD11BDAu;
  uint32_t x0[5], x1[5];
  #pragma unroll
  for (int i = 0; i < 5; ++i) { x0[i] = xa[i] + k0; x1[i] = xb[i] + k1; }
  TF5_R(13) TF5_R(15) TF5_R(26) TF5_R(6)  TF5_INJ(k1, k2 + 1u)
  TF5_R(17) TF5_R(29) TF5_R(16) TF5_R(24) TF5_INJ(k2, k0 + 2u)
  TF5_R(13) TF5_R(15) TF5_R(26) TF5_R(6)  TF5_INJ(k0, k1 + 3u)
  TF5_R(17) TF5_R(29) TF5_R(16) TF5_R(24) TF5_INJ(k1, k2 + 4u)
  TF5_R(13) TF5_R(15) TF5_R(26) TF5_R(6)  TF5_INJ(k2, k0 + 5u)
  #pragma unroll
  for (int i = 0; i < 5; ++i) { oa[i] = x0[i]; ob[i] = x1[i]; }
}

// exp-race form: argmax(l + gumbel) == argmin( (-ln u) * exp(-l) ).
#define NLN2F -0.6931471805599453f
#define NEG2LOG2E -2.8853900817779268f
__device__ __forceinline__ float exp_draw(uint32_t bits) {
  float u = __uint_as_float((bits >> 9) | 0x3f800000u) - 1.0f;
  u = fmaxf(u, 1.17549435e-38f);
  return NLN2F * __log2f(u);   // -ln(u) >= 0
}

// ---------------------------------------------------------------------------
// sample5 body (FULL pair, argmin + windows + acc; fallback path only).
// Counter identities (sC = BC*HW, halfn = 2.5*sC, eU = u*HW+p, eV = eU+sC/2):
//   u: s0,s1,s2 = o0(eU+t*sC); s3 = o1(eV), s4 = o1(eV+sC)
//   v: s0,s1    = o0(eV+t*sC); s2 = o1(eU), s3 = o1(eU+sC), s4 = o1(eU+2sC)
// Winner via uint-key argmin: score > 0 is uint-monotone in its float bits;
// key = (bits & ~0xFFF) | p -> single v_min_u32 per draw.
// ---------------------------------------------------------------------------
template <int NT>
__device__ void sample5_body(const unsigned short* __restrict__ CS,
    float* __restrict__ acc, uint32_t key0, uint32_t key1, int BC, float scale,
    int u, unsigned* kmin, float* wsum) {
  const int v = u + (BC >> 1);
  const uint32_t sC = (uint32_t)BC * (uint32_t)HW;
  const uint32_t halfn = sC * 2u + (sC >> 1);
  const unsigned short* rowU = CS + (size_t)u * HW;
  const unsigned short* rowV = CS + (size_t)v * HW;
  const int tid = threadIdx.x;
  const int lane = tid & 63;

  if (tid < 10) { kmin[tid] = 0xFFFFFFFFu; wsum[tid] = 0.f; }

  unsigned bk[10];
  #pragma unroll
  for (int k = 0; k < 10; ++k) bk[k] = 0xFFFFFFFFu;

  const uint32_t baseU0 = (uint32_t)u * (uint32_t)HW;
  const uint32_t baseV0 = (uint32_t)v * (uint32_t)HW;
  for (int p = tid; p < HW; p += NT) {
    float wu = __builtin_amdgcn_exp2f(bf2f(rowU[p]) * NEG2LOG2E);  // exp(-2c)
    float wv = __builtin_amdgcn_exp2f(bf2f(rowV[p]) * NEG2LOG2E);
    uint32_t eU = baseU0 + (uint32_t)p;
    uint32_t eV = baseV0 + (uint32_t)p;
    uint32_t xa[5] = {eU, eU + sC, eU + 2 * sC, eV, eV + sC};
    uint32_t xb[5] = {eU + halfn, eU + sC + halfn, eU + 2 * sC + halfn,
                      eV + halfn, eV + sC + halfn};
    uint32_t oa[5], ob[5];
    threefry5(key0, key1, xa, xb, oa, ob);
    uint32_t wds[10] = {oa[0], oa[1], oa[2], ob[3], ob[4],   // u s0..s4
                        oa[3], oa[4], ob[0], ob[1], ob[2]};  // v s0..s4
    #pragma unroll
    for (int k = 0; k < 10; ++k) {
      float s = exp_draw(wds[k]) * (k < 5 ? wu : wv);
      unsigned key = (__float_as_uint(s) & 0xFFFFF000u) | (unsigned)p;
      bk[k] = bk[k] < key ? bk[k] : key;
    }
  }

  __syncthreads();  // kmin/wsum init visible
  #pragma unroll
  for (int k = 0; k < 10; ++k) {
    unsigned kv = bk[k];
    #pragma unroll
    for (int o = 32; o; o >>= 1) {
      unsigned ov = __shfl_xor(kv, o);
      kv = kv < ov ? kv : ov;
    }
    if (lane == 0) atomicMin(&kmin[k], kv);
  }
  __syncthreads();

  for (int idx = tid; idx < 1210; idx += NT) {
    int win = idx / 121, j = idx - win * 121;
    int bidx = (int)(kmin[win] & 0xFFFu);
    int py = bidx / 56, px = bidx % 56;
    int yy = py + j / 11 - 5, xx = px + j % 11 - 5;
    if (yy >= 0 && yy < 56 && xx >= 0 && xx < 56) {
      const unsigned short* row = (win < 5) ? rowU : rowV;
      atomicAdd(&wsum[win], bf2f(row[yy * 56 + xx]));
    }
  }
  __syncthreads();
  if (tid == 0) {
    float t = 0.f;
    #pragma unroll
    for (int k = 0; k < 10; ++k) t += wsum[k];
    atomicAdd(acc, t * scale);
  }
}

// standalone sampling kernel (fallback path for stages 1 and 2)
template <int NT>
__global__ __launch_bounds__(NT) void sample5_k(const unsigned short* __restrict__ CS,
    float* __restrict__ acc, uint32_t key0, uint32_t key1, int BC, float scale) {
  __shared__ unsigned kmin[10];
  __shared__ float wsum[10];
  sample5_body<NT>(CS, acc, key0, key1, BC, scale, blockIdx.x, kmin, wsum);
}

// ---------------------------------------------------------------------------
// HALF-pair argmin (phase A): pixels [half*1568,(half+1)*1568) of pair u.
// NO windows, NO acc, NO device atomics/fences (round-9 lesson: mid-kernel
// device fences force cross-XCD L2 invalidation -> 2x HBM traffic, 26% VALU).
// Result: 10 block-local minima -> PLAIN stores to a dedicated global slot;
// the phase-B kernel launch boundary provides the coherence for free.
// Keys embed the global pixel index -> bit-exact split.
// ---------------------------------------------------------------------------
template <int NT>
__device__ void sample5_half_argmin(const unsigned short* __restrict__ CS,
    uint32_t key0, uint32_t key1, int BC, int u, int half,
    unsigned* __restrict__ outk, unsigned* kmin) {
  const int v = u + (BC >> 1);
  const uint32_t sC = (uint32_t)BC * (uint32_t)HW;
  const uint32_t halfn = sC * 2u + (sC >> 1);
  const unsigned short* rowU = CS + (size_t)u * HW;
  const unsigned short* rowV = CS + (size_t)v * HW;
  const int tid = threadIdx.x;
  const int lane = tid & 63;

  if (tid < 10) kmin[tid] = 0xFFFFFFFFu;

  unsigned bk[10];
  #pragma unroll
  for (int k = 0; k < 10; ++k) bk[k] = 0xFFFFFFFFu;

  const uint32_t baseU0 = (uint32_t)u * (uint32_t)HW;
  const uint32_t baseV0 = (uint32_t)v * (uint32_t)HW;
  const int pEnd = (half + 1) * (HW / 2);
  for (int p = half * (HW / 2) + tid; p < pEnd; p += NT) {
    float wu = __builtin_amdgcn_exp2f(bf2f(rowU[p]) * NEG2LOG2E);  // exp(-2c)
    float wv = __builtin_amdgcn_exp2f(bf2f(rowV[p]) * NEG2LOG2E);
    uint32_t eU = baseU0 + (uint32_t)p;
    uint32_t eV = baseV0 + (uint32_t)p;
    uint32_t xa[5] = {eU, eU + sC, eU + 2 * sC, eV, eV + sC};
    uint32_t xb[5] = {eU + halfn, eU + sC + halfn, eU + 2 * sC + halfn,
                      eV + halfn, eV + sC + halfn};
    uint32_t oa[5], ob[5];
    threefry5(key0, key1, xa, xb, oa, ob);
    uint32_t wds[10] = {oa[0], oa[1], oa[2], ob[3], ob[4],   // u s0..s4
                        oa[3], oa[4], ob[0], ob[1], ob[2]};  // v s0..s4
    #pragma unroll
    for (int k = 0; k < 10; ++k) {
      float s = exp_draw(wds[k]) * (k < 5 ? wu : wv);
      unsigned key = (__float_as_uint(s) & 0xFFFFF000u) | (unsigned)p;
      bk[k] = bk[k] < key ? bk[k] : key;
    }
  }

  __syncthreads();  // kmin init visible
  #pragma unroll
  for (int k = 0; k < 10; ++k) {
    unsigned kv = bk[k];
    #pragma unroll
    for (int o = 32; o; o >>= 1) {
      unsigned ov = __shfl_xor(kv, o);
      kv = kv < ov ? kv : ov;
    }
    if (lane == 0) atomicMin(&kmin[k], kv);
  }
  __syncthreads();
  if (tid < 10) outk[tid] = kmin[tid];   // plain store, dedicated slot
}

// ---------------------------------------------------------------------------
// MEGA phase A: 2*nPairs half-blocks + finals on the FIRST 512 blocks, done
// BEFORE their sampling half. Rationale (rounds 6-9): cohorts complete in
// lockstep, so post-pair finals always form an exposed all-memory burst.
// Finals-first on 2 blocks/CU leaves 6 blocks/CU (24 waves) sampling during
// the ~33us final drain -- 24 x ~3.75%/wave ~ 90% VALU -- then those blocks
// join sampling. 6144 half-blocks = 3 full-residency cohorts at the
// measured-efficient 8 blocks/CU; no cross-block sync anywhere.
// Pair list: [0,512) s1 (CS1,A0/A1,BC=1024), [512,1024) s2 (CS2,A2/B0,1024),
//            [1024,3072) s3 (CS3,B1/B2,4096).
// ---------------------------------------------------------------------------
__device__ __forceinline__ void final_chunk(int chunk,
    const unsigned short* __restrict__ Y3, const float* __restrict__ X,
    const float* __restrict__ sc, const float* __restrict__ sh,
    float* __restrict__ out) {
  size_t i = ((size_t)chunk * 256 + threadIdx.x) * 4;
  int c = (int)((i / HW) % 256);
  float a = sc[c], d = sh[c];
  uint2 yd = *(const uint2*)&Y3[i];
  float4 xv = *(const float4*)&X[i];
  float4 r;
  r.x = fmaxf(0.f, fmaf(bf2f((unsigned short)(yd.x & 0xffff)), a, d) + xv.x);
  r.y = fmaxf(0.f, fmaf(bf2f((unsigned short)(yd.x >> 16)),    a, d) + xv.y);
  r.z = fmaxf(0.f, fmaf(bf2f((unsigned short)(yd.y & 0xffff)), a, d) + xv.z);
  r.w = fmaxf(0.f, fmaf(bf2f((unsigned short)(yd.y >> 16)),    a, d) + xv.w);
  *(float4*)&out[i] = r;
}

__global__ __launch_bounds__(256, 8) void mega_argmin_k(
    const unsigned short* __restrict__ CS1, const unsigned short* __restrict__ CS2,
    const unsigned short* __restrict__ CS3,
    const unsigned short* __restrict__ Y3, const float* __restrict__ X,
    const float* __restrict__ sc, const float* __restrict__ sh,
    float* __restrict__ out, unsigned* __restrict__ bkmin,
    uint32_t A0, uint32_t A1, uint32_t A2, uint32_t B0, uint32_t B1, uint32_t B2,
    int pairStart, int finb) {
  __shared__ unsigned kmin[10];
  const int g = blockIdx.x;
  if (g < finb)  // finals FIRST on 2 blocks/CU; sampling continues elsewhere
    for (int cc = g; cc < 12544; cc += finb)
      final_chunk(cc, Y3, X, sc, sh, out);
  const int lp = g >> 1, half = g & 1;
  const int pi = pairStart + lp;
  const unsigned short* CSp; int u; uint32_t k0, k1; int BC;
  if (pi < 512)       { CSp = CS1; u = pi;        k0 = A0; k1 = A1; BC = 1024; }
  else if (pi < 1024) { CSp = CS2; u = pi - 512;  k0 = A2; k1 = B0; BC = 1024; }
  else                { CSp = CS3; u = pi - 1024; k0 = B1; k1 = B2; BC = 4096; }
  sample5_half_argmin<256>(CSp, k0, k1, BC, u, half, bkmin + (size_t)g * 10, kmin);
}

// ---------------------------------------------------------------------------
// MEGA phase B: combine half minima (kernel boundary = coherence), 11x11
// window sums, acc accumulation, scalar tail. 4 pairs per block.
// ---------------------------------------------------------------------------
__global__ __launch_bounds__(256) void combine_k(
    const unsigned short* __restrict__ CS1, const unsigned short* __restrict__ CS2,
    const unsigned short* __restrict__ CS3,
    const unsigned* __restrict__ bkmin, float* __restrict__ accp,
    unsigned* __restrict__ done, float* __restrict__ out,
    float s64, float s256, int pairStart, int nPairs) {
  __shared__ unsigned kmin[10];
  __shared__ float wsum[10];
  const int tid = threadIdx.x;
  float psum = 0.f;
  for (int j = 0; j < 4; ++j) {
    const int rp = blockIdx.x * 4 + j;
    if (rp >= nPairs) break;
    const int pi = pairStart + rp;
    const unsigned short* rowU; const unsigned short* rowV; float scale;
    if (pi < 512) {
      rowU = CS1 + (size_t)pi * HW; rowV = CS1 + (size_t)(pi + 512) * HW; scale = s64;
    } else if (pi < 1024) {
      int u = pi - 512;
      rowU = CS2 + (size_t)u * HW; rowV = CS2 + (size_t)(u + 512) * HW; scale = s64;
    } else {
      int u = pi - 1024;
      rowU = CS3 + (size_t)u * HW; rowV = CS3 + (size_t)(u + 2048) * HW; scale = s256;
    }
    if (tid < 10) {
      unsigned a = bkmin[(size_t)(2 * rp) * 10 + tid];
      unsigned b = bkmin[(size_t)(2 * rp + 1) * 10 + tid];
      kmin[tid] = a < b ? a : b;
      wsum[tid] = 0.f;
    }
    __syncthreads();
    for (int idx = tid; idx < 1210; idx += 256) {
      int win = idx / 121, jj = idx - win * 121;
      int bidx = (int)(kmin[win] & 0xFFFu);
      int py = bidx / 56, px = bidx % 56;
      int yy = py + jj / 11 - 5, xx = px + jj % 11 - 5;
      if (yy >= 0 && yy < 56 && xx >= 0 && xx < 56) {
        const unsigned short* row = (win < 5) ? rowU : rowV;
        atomicAdd(&wsum[win], bf2f(row[yy * 56 + xx]));
      }
    }
    __syncthreads();
    if (tid == 0) {
      float t = 0.f;
      #pragma unroll
      for (int k = 0; k < 10; ++k) t += wsum[k];
      psum += t * scale;
    }
    __syncthreads();  // protect wsum reinit next iteration
  }
  if (tid == 0) {
    atomicAdd(accp, psum);
    __threadfence();
    unsigned prev = atomicAdd(done, 1u);
    if (prev == (unsigned)(gridDim.x - 1))
      out[12845056] = atomicAdd(accp, 0.f);  // atomic read through coherent path
  }
}

// ---------------------------------------------------------------------------
// weight prep: invwn[384] (1/(||w||+eps)) + bf16 weight conversion.
// ---------------------------------------------------------------------------
__global__ void wprep_k(const float* __restrict__ w1, const float* __restrict__ w2,
                        const float* __restrict__ w3, float* __restrict__ invwn,
                        unsigned short* __restrict__ W1b, unsigned short* __restrict__ W2tb,
                        unsigned short* __restrict__ W3b) {
  int i = blockIdx.x * 256 + threadIdx.x;
  if (i < 16384) {
    W1b[i] = f2bf(w1[i]);
  } else if (i < 53248) {
    int o = i - 16384;
    int co = o / 576, r = o % 576, tap = r >> 6, ci = r & 63;
    W2tb[o] = f2bf(w2[co * 576 + ci * 9 + tap]);
  } else if (i < 69632) {
    int o = i - 53248;
    W3b[o] = f2bf(w3[o]);
  } else {
    int t = i - 69632;
    if (t < 64) {
      float s = 0.f;
      for (int k = 0; k < 256; k++) { float v = w1[t * 256 + k]; s = fmaf(v, v, s); }
      invwn[t] = 1.0f / (sqrtf(s) + 1e-6f);
    } else if (t < 128) {
      int c = t - 64; float s = 0.f;
      for (int k = 0; k < 576; k++) { float v = w2[c * 576 + k]; s = fmaf(v, v, s); }
      invwn[t] = 1.0f / (sqrtf(s) + 1e-6f);
    } else if (t < 384) {
      int c = t - 128; float s = 0.f;
      for (int k = 0; k < 64; k++) { float v = w3[c * 64 + k]; s = fmaf(v, v, s); }
      invwn[t] = 1.0f / (sqrtf(s) + 1e-6f);
    }
  }
}

// ---------------------------------------------------------------------------
// BN finalize from per-block partials, channel-major [co][nblk].
// ---------------------------------------------------------------------------
__global__ __launch_bounds__(256) void bn_fin(const float* __restrict__ Sp,
    const float* __restrict__ Qp, const float* __restrict__ g,
    const float* __restrict__ b, float* __restrict__ sc, float* __restrict__ sh,
    int nblk) {
  const int c = blockIdx.x, tid = threadIdx.x;
  const float* rs = Sp + (size_t)c * nblk;
  const float* rq = Qp + (size_t)c * nblk;
  float s = 0.f, q = 0.f;
  for (int i = tid; i < nblk; i += 256) { s += rs[i]; q += rq[i]; }
  #pragma unroll
  for (int o = 32; o; o >>= 1) { s += __shfl_xor(s, o); q += __shfl_xor(q, o); }
  __shared__ float S[4], Q[4];
  int lane = tid & 63, wave = tid >> 6;
  if (lane == 0) { S[wave] = s; Q[wave] = q; }
  __syncthreads();
  if (tid == 0) {
    float st = S[0] + S[1] + S[2] + S[3];
    float qt = Q[0] + Q[1] + Q[2] + Q[3];
    float mean = st * (1.0f / (float)NPIX);
    float var = qt * (1.0f / (float)NPIX) - mean * mean;  // biased, jnp.var
    float sv = g[c] / sqrtf(var + 1e-5f);
    sc[c] = sv; sh[c] = b[c] - mean * sv;
  }
}

// ---------------------------------------------------------------------------
// conv1: 1x1 256->64 MFMA. Block = 64px x 64co, grid (49,16).
// ---------------------------------------------------------------------------
__global__ __launch_bounds__(256) void conv1_mfma(
    const float* __restrict__ X, const unsigned short* __restrict__ Wb,
    const float* __restrict__ invwn, unsigned short* __restrict__ Y1,
    unsigned short* __restrict__ CS, float* __restrict__ Sp, float* __restrict__ Qp) {
#define ST1 264
#define NB1 784
  __shared__ __align__(16) unsigned short bq[64 * ST1];
  __shared__ float sqp[4][64];
  __shared__ float ixn[64];
  const int p0 = blockIdx.x * 64, b = blockIdx.y;
  const int bid = b * 49 + blockIdx.x;
  const int tid = threadIdx.x;
  const int lane = tid & 63, wave = tid >> 6;
  const int m = lane & 15, quad = lane >> 4;
  const int co0 = wave * 16;
  const float* Xb = X + (size_t)b * 256 * HW + p0;

  bf16x8 afr[8];
  const unsigned short* wrow = Wb + (co0 + m) * 256 + quad * 8;
  #pragma unroll
  for (int k = 0; k < 8; ++k) afr[k] = *(const bf16x8*)(wrow + k * 32);

  {
    const int px = tid & 63, rg = tid >> 6;
    float sq = 0.f;
    #pragma unroll
    for (int it = 0; it < 16; ++it) {
      int ci = rg * 64 + it * 4;
      float v0 = Xb[(size_t)(ci + 0) * HW + px];
      float v1 = Xb[(size_t)(ci + 1) * HW + px];
      float v2 = Xb[(size_t)(ci + 2) * HW + px];
      float v3 = Xb[(size_t)(ci + 3) * HW + px];
      sq += v0 * v0 + v1 * v1 + v2 * v2 + v3 * v3;
      *(uint2*)&bq[px * ST1 + ci] = make_uint2(pk2(v0, v1), pk2(v2, v3));
    }
    sqp[rg][px] = sq;
  }
  __syncthreads();
  if (tid < 64)
    ixn[tid] = 1.0f / (sqrtf(sqp[0][tid] + sqp[1][tid] + sqp[2][tid] + sqp[3][tid]) + 1e-6f);
  __syncthreads();

  f32x4 acc[4];
  #pragma unroll
  for (int nt = 0; nt < 4; ++nt) acc[nt] = (f32x4)0.f;
  #pragma unroll
  for (int nt = 0; nt < 4; ++nt) {
    const unsigned short* brow = &bq[(nt * 16 + m) * ST1 + quad * 8];
    #pragma unroll
    for (int k = 0; k < 8; ++k) {
      bf16x8 bfrag = *(const bf16x8*)(brow + k * 32);
      acc[nt] = MFMA16(afr[k], bfrag, acc[nt]);
    }
  }

  float s[4] = {0, 0, 0, 0}, q[4] = {0, 0, 0, 0};
  #pragma unroll
  for (int nt = 0; nt < 4; ++nt) {
    int px = nt * 16 + m;
    size_t bp = (size_t)b * HW + p0 + px;
    float ix = ixn[px];
    *(uint2*)&Y1[bp * 64 + co0 + quad * 4] =
        make_uint2(pk2(acc[nt][0], acc[nt][1]), pk2(acc[nt][2], acc[nt][3]));
    #pragma unroll
    for (int r = 0; r < 4; ++r) {
      int co = co0 + quad * 4 + r;
      float v = acc[nt][r];
      CS[((size_t)b * 64 + co) * HW + p0 + px] = f2bf(v * invwn[co] * ix);
      s[r] += v; q[r] = fmaf(v, v, q[r]);
    }
  }
  #pragma unroll
  for (int r = 0; r < 4; ++r) {
    float ss = s[r], qq = q[r];
    #pragma unroll
    for (int o = 8; o; o >>= 1) { ss += __shfl_xor(ss, o); qq += __shfl_xor(qq, o); }
    if (m == 0) {
      int co = co0 + quad * 4 + r;
      Sp[(size_t)co * NB1 + bid] = ss; Qp[(size_t)co * NB1 + bid] = qq;
    }
  }
#undef NB1
#undef ST1
}

// ---------------------------------------------------------------------------
// conv2: 3x3 64->64 pad1, implicit-GEMM MFMA. grid (56,16). CS bf16.
// FUSED x_norm: ts tile IS relu(bn1(y1)) (zero-padded) == exactly what
// part(pixel) = sum_ci t1^2 needs for rows h-1..h+1; spart + 3x3 box in
// the epilogue.
// ---------------------------------------------------------------------------
__global__ __launch_bounds__(256) void conv2_mfma(
    const unsigned short* __restrict__ Y1, const unsigned short* __restrict__ W2tb,
    const float* __restrict__ invwn,
    const float* __restrict__ sc1, const float* __restrict__ sh1,
    unsigned short* __restrict__ Y2, unsigned short* __restrict__ CS,
    float* __restrict__ Sp, float* __restrict__ Qp) {
#define STW 72
#define NB2 896
  __shared__ __align__(16) unsigned short ts[3 * 66 * STW];
  __shared__ float scl[64], shl[64];
  __shared__ float spart[3 * 56];
  const int h = blockIdx.x, b = blockIdx.y;
  const int bid = b * 56 + h;
  const int tid = threadIdx.x;
  const int lane = tid & 63, wave = tid >> 6;
  const int m = lane & 15, quad = lane >> 4;
  const int co0 = wave * 16;
  if (tid < 64) { scl[tid] = sc1[tid]; shl[tid] = sh1[tid]; }

  bf16x8 afr[18];
  #pragma unroll
  for (int ks = 0; ks < 18; ++ks)
    afr[ks] = *(const bf16x8*)(W2tb + (co0 + m) * 576 + ks * 32 + quad * 8);
  __syncthreads();

  for (int l = tid; l < 6336; l += 256) {  // 3 rows x 66 cols x 32 ci-pairs
    int cp = l & 31, cc = (l >> 5) % 66, dy = l / 2112;
    int yy = h - 1 + dy, xx = cc - 1;
    unsigned pkv = 0u;
    if (yy >= 0 && yy < 56 && xx >= 0 && xx < 56) {
      unsigned d = *(const unsigned*)&Y1[((size_t)b * HW + yy * 56 + xx) * 64 + cp * 2];
      float v0 = bf2f((unsigned short)(d & 0xffff));
      float v1 = bf2f((unsigned short)(d >> 16));
      v0 = fmaxf(0.f, fmaf(v0, scl[cp * 2], shl[cp * 2]));
      v1 = fmaxf(0.f, fmaf(v1, scl[cp * 2 + 1], shl[cp * 2 + 1]));
      pkv = pk2(v0, v1);
    }
    *(unsigned*)&ts[(dy * 66 + cc) * STW + cp * 2] = pkv;
  }
  __syncthreads();

  // spart[dy][x] = sum_ci ts[dy][x+1][ci]^2
  if (tid < 168) {
    int dy = tid / 56, x = tid - dy * 56;
    const unsigned* row = (const unsigned*)&ts[(dy * 66 + x + 1) * STW];
    float s = 0.f;
    #pragma unroll
    for (int j = 0; j < 32; ++j) {
      unsigned d = row[j];
      float v0 = bf2f((unsigned short)(d & 0xffff));
      float v1 = bf2f((unsigned short)(d >> 16));
      s = fmaf(v0, v0, s); s = fmaf(v1, v1, s);
    }
    spart[tid] = s;
  }
  __syncthreads();

  f32x4 acc[4];
  #pragma unroll
  for (int nt = 0; nt < 4; ++nt) acc[nt] = (f32x4)0.f;
  #pragma unroll
  for (int nt = 0; nt < 4; ++nt) {
    #pragma unroll
    for (int ks = 0; ks < 18; ++ks) {
      int tap = ks >> 1, half = ks & 1;
      int dy = tap / 3, dx = tap % 3;
      bf16x8 bfrag = *(const bf16x8*)&ts[(dy * 66 + nt * 16 + m + dx) * STW + half * 32 + quad * 8];
      acc[nt] = MFMA16(afr[ks], bfrag, acc[nt]);
    }
  }

  float s[4] = {0, 0, 0, 0}, q[4] = {0, 0, 0, 0};
  #pragma unroll
  for (int nt = 0; nt < 4; ++nt) {
    int px = nt * 16 + m;
    bool valid = px < 56;
    int pix = h * 56 + px;
    if (valid) {
      float tot = 0.f;
      #pragma unroll
      for (int dy = 0; dy < 3; ++dy) {
        #pragma unroll
        for (int dx = -1; dx <= 1; ++dx) {
          int xx = px + dx;
          if (xx >= 0 && xx < 56) tot += spart[dy * 56 + xx];
        }
      }
      float ix = 1.0f / (sqrtf(tot) + 1e-6f);
      size_t bp = (size_t)b * HW + pix;
      *(uint2*)&Y2[bp * 64 + co0 + quad * 4] =
          make_uint2(pk2(acc[nt][0], acc[nt][1]), pk2(acc[nt][2], acc[nt][3]));
      #pragma unroll
      for (int r = 0; r < 4; ++r) {
        int co = co0 + quad * 4 + r;
        CS[((size_t)b * 64 + co) * HW + pix] = f2bf(acc[nt][r] * invwn[co] * ix);
      }
    }
    #pragma unroll
    for (int r = 0; r < 4; ++r) {
      float v = valid ? acc[nt][r] : 0.f;
      s[r] += v; q[r] = fmaf(v, v, q[r]);
    }
  }
  #pragma unroll
  for (int r = 0; r < 4; ++r) {
    float ss = s[r], qq = q[r];
    #pragma unroll
    for (int o = 8; o; o >>= 1) { ss += __shfl_xor(ss, o); qq += __shfl_xor(qq, o); }
    if (m == 0) {
      int co = co0 + quad * 4 + r;
      Sp[(size_t)co * NB2 + bid] = ss; Qp[(size_t)co * NB2 + bid] = qq;
    }
  }
#undef NB2
#undef STW
}

// ---------------------------------------------------------------------------
// conv3: 1x1 64->256 MFMA. grid (49,16). Outputs y3 bf16 + cos3 bf16.
// ---------------------------------------------------------------------------
__global__ __launch_bounds__(256) void conv3_mfma(
    const unsigned short* __restrict__ Y2, const unsigned short* __restrict__ W3b,
    const float* __restrict__ invwn,
    const float* __restrict__ sc2, const float* __restrict__ sh2,
    unsigned short* __restrict__ Y3, unsigned short* __restrict__ CS,
    float* __restrict__ Sp, float* __restrict__ Qp) {
#define ST3 72
#define NB3 784
  __shared__ __align__(16) unsigned short bq[64 * ST3];
  __shared__ float scl[64], shl[64], sqp[4][64], ixn[64];
  const int p0 = blockIdx.x * 64, b = blockIdx.y;
  const int bid = b * 49 + blockIdx.x;
  const int tid = threadIdx.x;
  const int lane = tid & 63, wave = tid >> 6;
  const int m = lane & 15, quad = lane >> 4;
  const int co0 = wave * 64;
  if (tid < 64) { scl[tid] = sc2[tid]; shl[tid] = sh2[tid]; }

  bf16x8 afr[4][2];
  #pragma unroll
  for (int mt = 0; mt < 4; ++mt)
    #pragma unroll
    for (int k = 0; k < 2; ++k)
      afr[mt][k] = *(const bf16x8*)(W3b + (co0 + mt * 16 + m) * 64 + k * 32 + quad * 8);
  __syncthreads();

  {
    const int cp = tid & 31, pxg = tid >> 5;
    #pragma unroll
    for (int it = 0; it < 8; ++it) {
      int px = pxg * 8 + it;
      unsigned d = *(const unsigned*)&Y2[((size_t)b * HW + p0 + px) * 64 + cp * 2];
      float v0 = bf2f((unsigned short)(d & 0xffff));
      float v1 = bf2f((unsigned short)(d >> 16));
      v0 = fmaxf(0.f, fmaf(v0, scl[cp * 2], shl[cp * 2]));
      v1 = fmaxf(0.f, fmaf(v1, scl[cp * 2 + 1], shl[cp * 2 + 1]));
      *(unsigned*)&bq[px * ST3 + cp * 2] = pk2(v0, v1);
    }
  }
  __syncthreads();
  {
    const int px = tid & 63, hh = tid >> 6;
    const unsigned short* row = &bq[px * ST3 + hh * 16];
    float sq = 0.f;
    #pragma unroll
    for (int e = 0; e < 16; ++e) { float v = bf2f(row[e]); sq = fmaf(v, v, sq); }
    sqp[hh][px] = sq;
  }
  __syncthreads();
  if (tid < 64)
    ixn[tid] = 1.0f / (sqrtf(sqp[0][tid] + sqp[1][tid] + sqp[2][tid] + sqp[3][tid]) + 1e-6f);
  __syncthreads();

  f32x4 acc[4][4];
  #pragma unroll
  for (int mt = 0; mt < 4; ++mt)
    #pragma unroll
    for (int nt = 0; nt < 4; ++nt) acc[mt][nt] = (f32x4)0.f;
  #pragma unroll
  for (int nt = 0; nt < 4; ++nt) {
    const unsigned short* brow = &bq[(nt * 16 + m) * ST3 + quad * 8];
    bf16x8 b0 = *(const bf16x8*)(brow);
    bf16x8 b1 = *(const bf16x8*)(brow + 32);
    #pragma unroll
    for (int mt = 0; mt < 4; ++mt) {
      acc[mt][nt] = MFMA16(afr[mt][0], b0, acc[mt][nt]);
      acc[mt][nt] = MFMA16(afr[mt][1], b1, acc[mt][nt]);
    }
  }

  #pragma unroll
  for (int mt = 0; mt < 4; ++mt) {
    float s[4] = {0, 0, 0, 0}, q[4] = {0, 0, 0, 0};
    #pragma unroll
    for (int nt = 0; nt < 4; ++nt) {
      int px = nt * 16 + m;
      float ix = ixn[px];
      #pragma unroll
      for (int r = 0; r < 4; ++r) {
        int co = co0 + mt * 16 + quad * 4 + r;
        float v = acc[mt][nt][r];
        size_t off = ((size_t)b * 256 + co) * HW + p0 + px;
        Y3[off] = f2bf(v);
        CS[off] = f2bf(v * invwn[co] * ix);
        s[r] += v; q[r] = fmaf(v, v, q[r]);
      }
    }
    #pragma unroll
    for (int r = 0; r < 4; ++r) {
      float ss = s[r], qq = q[r];
      #pragma unroll
      for (int o = 8; o; o >>= 1) { ss += __shfl_xor(ss, o); qq += __shfl_xor(qq, o); }
      if (m == 0) {
        int co = co0 + mt * 16 + quad * 4 + r;
        Sp[(size_t)co * NB3 + bid] = ss; Qp[(size_t)co * NB3 + bid] = qq;
      }
    }
  }
#undef NB3
#undef ST3
}

// ---------------------------------------------------------------------------
extern "C" void kernel_launch(void* const* d_in, const int* in_sizes, int n_in,
                              void* d_out, int out_size, void* d_ws, size_t ws_size,
                              hipStream_t stream) {
  (void)in_sizes; (void)n_in; (void)out_size;
  const float* x  = (const float*)d_in[0];
  const float* w1 = (const float*)d_in[1];
  const float* w2 = (const float*)d_in[2];
  const float* w3 = (const float*)d_in[3];
  const float* g1 = (const float*)d_in[4];
  const float* b1 = (const float*)d_in[5];
  const float* g2 = (const float*)d_in[6];
  const float* b2 = (const float*)d_in[7];
  const float* g3 = (const float*)d_in[8];
  const float* b3 = (const float*)d_in[9];
  float* out = (float*)d_out;
  float* ws = (float*)d_ws;

  // workspace layout (float units; bf16 buffers use elems/2 float units)
  size_t o = 0;
  unsigned short* y3b  = (unsigned short*)(ws + o); o += 6422528;  // 12845056 bf16
  unsigned short* cos3 = (unsigned short*)(ws + o); o += 6422528;  // 12845056 bf16
  unsigned short* CSb  = (unsigned short*)(ws + o); o += 1605632;  // 3211264 bf16
  unsigned short* y1b  = (unsigned short*)(ws + o); o += 1605632;  // 3211264 bf16
  unsigned short* y2b  = (unsigned short*)(ws + o); o += 1605632;  // 3211264 bf16
  unsigned short* W1b  = (unsigned short*)(ws + o); o += 8192;     // 16384 bf16
  unsigned short* W2tb = (unsigned short*)(ws + o); o += 18432;    // 36864 bf16
  unsigned short* W3b  = (unsigned short*)(ws + o); o += 8192;     // 16384 bf16
  float* invwn = ws + o; o += 384;
  float* Sp1 = ws + o; o += 64 * 784;   float* Qp1 = ws + o; o += 64 * 784;
  float* Sp2 = ws + o; o += 64 * 896;   float* Qp2 = ws + o; o += 64 * 896;
  float* Sp3 = ws + o; o += 256 * 784;  float* Qp3 = ws + o; o += 256 * 784;
  float* acc = ws + o; o += 1;
  unsigned* done = (unsigned*)(ws + o); o += 1;
  unsigned* bkmin = (unsigned*)(ws + o); o += 61440;  // 6144 blocks x 10 keys
  float* sc1 = ws + o; o += 64;  float* sh1 = ws + o; o += 64;
  float* sc2 = ws + o; o += 64;  float* sh2 = ws + o; o += 64;
  float* sc3 = ws + o; o += 256; float* sh3 = ws + o; o += 256;

  // Separate conv2-cosine buffer so stage-1/2 sampling can be deferred into
  // the mega kernels (CSb must survive conv2). Guarded by ws_size.
  const bool big = ws_size >= (o + 1605632) * sizeof(float);
  unsigned short* CS2b = big ? (unsigned short*)(ws + o) : CSb;

  hipMemsetAsync(acc, 0, 2 * sizeof(float), stream);  // acc + done

  // JAX: k0,k1,k2 = split(key(42), 3); (Ai,Bi) = threefry2x32((0,42),(i,i+3))
  uint32_t A0, B0, A1, B1, A2, B2;
  threefry2x32(0u, 42u, 0u, 3u, A0, B0);
  threefry2x32(0u, 42u, 1u, 4u, A1, B1);
  threefry2x32(0u, 42u, 2u, 5u, A2, B2);

  const float scale64  = 1.0f / (121.0f * 5.0f * 1024.0f);
  const float scale256 = 1.0f / (121.0f * 5.0f * 4096.0f);

  wprep_k<<<274, 256, 0, stream>>>(w1, w2, w3, invwn, W1b, W2tb, W3b);

  // conv pipeline (serial deps: conv1 -> bn1 -> conv2 -> bn2 -> conv3 -> bn3)
  conv1_mfma<<<dim3(49, 16), 256, 0, stream>>>(x, W1b, invwn, y1b, CSb, Sp1, Qp1);
  bn_fin<<<64, 256, 0, stream>>>(Sp1, Qp1, g1, b1, sc1, sh1, 784);
  if (!big)  // fallback: must sample CSb before conv2 overwrites it
    sample5_k<512><<<512, 512, 0, stream>>>(CSb, acc, A0, A1, 1024, scale64);
  conv2_mfma<<<dim3(56, 16), 256, 0, stream>>>(
      y1b, W2tb, invwn + 64, sc1, sh1, y2b, CS2b, Sp2, Qp2);
  bn_fin<<<64, 256, 0, stream>>>(Sp2, Qp2, g2, b2, sc2, sh2, 896);
  if (!big)
    sample5_k<512><<<512, 512, 0, stream>>>(CS2b, acc, A2, B0, 1024, scale64);
  conv3_mfma<<<dim3(49, 16), 256, 0, stream>>>(
      y2b, W3b, invwn + 128, sc2, sh2, y3b, cos3, Sp3, Qp3);
  bn_fin<<<256, 256, 0, stream>>>(Sp3, Qp3, g3, b3, sc3, sh3, 784);

  // Phase A: half-pair argmin (plain-store results) + finals-first on 512
  // blocks. Phase B: combine + windows + acc + scalar tail.
  if (big) {
    mega_argmin_k<<<6144, 256, 0, stream>>>(
        CSb, CS2b, cos3, y3b, x, sc3, sh3, out, bkmin,
        A0, A1, A2, B0, B1, B2, /*pairStart=*/0, /*finb=*/512);
    combine_k<<<768, 256, 0, stream>>>(
        CSb, CS2b, cos3, bkmin, acc, done, out,
        scale64, scale256, /*pairStart=*/0, /*nPairs=*/3072);
  } else {
    mega_argmin_k<<<4096, 256, 0, stream>>>(
        CSb, CS2b, cos3, y3b, x, sc3, sh3, out, bkmin,
        A0, A1, A2, B0, B1, B2, /*pairStart=*/1024, /*finb=*/512);
    combine_k<<<512, 256, 0, stream>>>(
        CSb, CS2b, cos3, bkmin, acc, done, out,
        scale64, scale256, /*pairStart=*/1024, /*nPairs=*/2048);
  }
}

// Round 11
// 365.174 us; speedup vs baseline: 2.2874x; 1.0896x over previous
//
#include <hip/hip_runtime.h>
#include <stdint.h>
#include <math.h>

// Problem constants: B=16, H=W=56, HW=3136, pipeline 256 -> 64 -> 64 -> 256
#define HW 3136
#define NPIX 50176  // 16*3136

// ---------------------------------------------------------------------------
// MFMA types & helpers (gfx950 v_mfma_f32_16x16x32_bf16)
// ---------------------------------------------------------------------------
typedef __attribute__((ext_vector_type(8))) short bf16x8;
typedef __attribute__((ext_vector_type(4))) float f32x4;
#define MFMA16(a, b, c) __builtin_amdgcn_mfma_f32_16x16x32_bf16(a, b, c, 0, 0, 0)

__device__ __forceinline__ unsigned short f2bf(float f) {  // RNE f32->bf16
  unsigned u = __float_as_uint(f);
  u = (u + 0x7fffu + ((u >> 16) & 1u)) >> 16;
  return (unsigned short)u;
}
__device__ __forceinline__ unsigned pk2(float a, float b) {
  return (unsigned)f2bf(a) | ((unsigned)f2bf(b) << 16);
}
__device__ __forceinline__ float bf2f(unsigned short h) {
  return __uint_as_float(((unsigned)h) << 16);
}

// ---------------------------------------------------------------------------
// threefry2x32 (Random123 / JAX-exact). ROTL = single v_alignbit via builtin.
// ---------------------------------------------------------------------------
#define ROTL32(v, r) __builtin_rotateleft32((uint32_t)(v), (r))

__host__ __device__ inline void threefry2x32(uint32_t k0, uint32_t k1,
                                             uint32_t x0, uint32_t x1,
                                             uint32_t& o0, uint32_t& o1) {
  uint32_t k2 = k0 ^ k1 ^ 0x1BD11BDAu;
  x0 += k0; x1 += k1;
  x0 += x1; x1 = ROTL32(x1, 13); x1 ^= x0;
  x0 += x1; x1 = ROTL32(x1, 15); x1 ^= x0;
  x0 += x1; x1 = ROTL32(x1, 26); x1 ^= x0;
  x0 += x1; x1 = ROTL32(x1, 6);  x1 ^= x0;
  x0 += k1; x1 += k2 + 1u;
  x0 += x1; x1 = ROTL32(x1, 17); x1 ^= x0;
  x0 += x1; x1 = ROTL32(x1, 29); x1 ^= x0;
  x0 += x1; x1 = ROTL32(x1, 16); x1 ^= x0;
  x0 += x1; x1 = ROTL32(x1, 24); x1 ^= x0;
  x0 += k2; x1 += k0 + 2u;
  x0 += x1; x1 = ROTL32(x1, 13); x1 ^= x0;
  x0 += x1; x1 = ROTL32(x1, 15); x1 ^= x0;
  x0 += x1; x1 = ROTL32(x1, 26); x1 ^= x0;
  x0 += x1; x1 = ROTL32(x1, 6);  x1 ^= x0;
  x0 += k0; x1 += k1 + 3u;
  x0 += x1; x1 = ROTL32(x1, 17); x1 ^= x0;
  x0 += x1; x1 = ROTL32(x1, 29); x1 ^= x0;
  x0 += x1; x1 = ROTL32(x1, 16); x1 ^= x0;
  x0 += x1; x1 = ROTL32(x1, 24); x1 ^= x0;
  x0 += k1; x1 += k2 + 4u;
  x0 += x1; x1 = ROTL32(x1, 13); x1 ^= x0;
  x0 += x1; x1 = ROTL32(x1, 15); x1 ^= x0;
  x0 += x1; x1 = ROTL32(x1, 26); x1 ^= x0;
  x0 += x1; x1 = ROTL32(x1, 6);  x1 ^= x0;
  x0 += k2; x1 += k0 + 5u;
  o0 = x0; o1 = x1;
}

// 5 threefry2x32 instances in lockstep (single-instr rotations, ILP=5).
#define TF5_R(r)                                            \
  _Pragma("unroll") for (int i = 0; i < 5; ++i) {           \
    x0[i] += x1[i]; x1[i] = ROTL32(x1[i], r) ^ x0[i];       \
  }
#define TF5_INJ(a, b)                                       \
  _Pragma("unroll") for (int i = 0; i < 5; ++i) {           \
    x0[i] += (a); x1[i] += (b);                             \
  }
__device__ __forceinline__ void threefry5(uint32_t k0, uint32_t k1,
    const uint32_t xa[5], const uint32_t xb[5], uint32_t oa[5], uint32_t ob[5]) {
  uint32_t k2 = k0 ^ k1 ^ 0x1BD11BDAu;
  uint32_t x0[5], x1[5];
  #pragma unroll
  for (int i = 0; i < 5; ++i) { x0[i] = xa[i] + k0; x1[i] = xb[i] + k1; }
  TF5_R(13) TF5_R(15) TF5_R(26) TF5_R(6)  TF5_INJ(k1, k2 + 1u)
  TF5_R(17) TF5_R(29) TF5_R(16) TF5_R(24) TF5_INJ(k2, k0 + 2u)
  TF5_R(13) TF5_R(15) TF5_R(26) TF5_R(6)  TF5_INJ(k0, k1 + 3u)
  TF5_R(17) TF5_R(29) TF5_R(16) TF5_R(24) TF5_INJ(k1, k2 + 4u)
  TF5_R(13) TF5_R(15) TF5_R(26) TF5_R(6)  TF5_INJ(k2, k0 + 5u)
  #pragma unroll
  for (int i = 0; i < 5; ++i) { oa[i] = x0[i]; ob[i] = x1[i]; }
}

// exp-race form: argmax(l + gumbel) == argmin( (-ln u) * exp(-l) ).
#define NLN2F -0.6931471805599453f
#define NEG2LOG2E -2.8853900817779268f
__device__ __forceinline__ float exp_draw(uint32_t bits) {
  float u = __uint_as_float((bits >> 9) | 0x3f800000u) - 1.0f;
  u = fmaxf(u, 1.17549435e-38f);
  return NLN2F * __log2f(u);   // -ln(u) >= 0
}

// ---------------------------------------------------------------------------
// sample5 body (FULL pair, argmin + windows + acc; fallback path only).
// Counter identities (sC = BC*HW, halfn = 2.5*sC, eU = u*HW+p, eV = eU+sC/2):
//   u: s0,s1,s2 = o0(eU+t*sC); s3 = o1(eV), s4 = o1(eV+sC)
//   v: s0,s1    = o0(eV+t*sC); s2 = o1(eU), s3 = o1(eU+sC), s4 = o1(eU+2sC)
// Winner via uint-key argmin: score > 0 is uint-monotone in its float bits;
// key = (bits & ~0xFFF) | p -> single v_min_u32 per draw.
// ---------------------------------------------------------------------------
template <int NT>
__device__ void sample5_body(const unsigned short* __restrict__ CS,
    float* __restrict__ acc, uint32_t key0, uint32_t key1, int BC, float scale,
    int u, unsigned* kmin, float* wsum) {
  const int v = u + (BC >> 1);
  const uint32_t sC = (uint32_t)BC * (uint32_t)HW;
  const uint32_t halfn = sC * 2u + (sC >> 1);
  const unsigned short* rowU = CS + (size_t)u * HW;
  const unsigned short* rowV = CS + (size_t)v * HW;
  const int tid = threadIdx.x;
  const int lane = tid & 63;

  if (tid < 10) { kmin[tid] = 0xFFFFFFFFu; wsum[tid] = 0.f; }

  unsigned bk[10];
  #pragma unroll
  for (int k = 0; k < 10; ++k) bk[k] = 0xFFFFFFFFu;

  const uint32_t baseU0 = (uint32_t)u * (uint32_t)HW;
  const uint32_t baseV0 = (uint32_t)v * (uint32_t)HW;
  for (int p = tid; p < HW; p += NT) {
    float wu = __builtin_amdgcn_exp2f(bf2f(rowU[p]) * NEG2LOG2E);  // exp(-2c)
    float wv = __builtin_amdgcn_exp2f(bf2f(rowV[p]) * NEG2LOG2E);
    uint32_t eU = baseU0 + (uint32_t)p;
    uint32_t eV = baseV0 + (uint32_t)p;
    uint32_t xa[5] = {eU, eU + sC, eU + 2 * sC, eV, eV + sC};
    uint32_t xb[5] = {eU + halfn, eU + sC + halfn, eU + 2 * sC + halfn,
                      eV + halfn, eV + sC + halfn};
    uint32_t oa[5], ob[5];
    threefry5(key0, key1, xa, xb, oa, ob);
    uint32_t wds[10] = {oa[0], oa[1], oa[2], ob[3], ob[4],   // u s0..s4
                        oa[3], oa[4], ob[0], ob[1], ob[2]};  // v s0..s4
    #pragma unroll
    for (int k = 0; k < 10; ++k) {
      float s = exp_draw(wds[k]) * (k < 5 ? wu : wv);
      unsigned key = (__float_as_uint(s) & 0xFFFFF000u) | (unsigned)p;
      bk[k] = bk[k] < key ? bk[k] : key;
    }
  }

  __syncthreads();  // kmin/wsum init visible
  #pragma unroll
  for (int k = 0; k < 10; ++k) {
    unsigned kv = bk[k];
    #pragma unroll
    for (int o = 32; o; o >>= 1) {
      unsigned ov = __shfl_xor(kv, o);
      kv = kv < ov ? kv : ov;
    }
    if (lane == 0) atomicMin(&kmin[k], kv);
  }
  __syncthreads();

  for (int idx = tid; idx < 1210; idx += NT) {
    int win = idx / 121, j = idx - win * 121;
    int bidx = (int)(kmin[win] & 0xFFFu);
    int py = bidx / 56, px = bidx % 56;
    int yy = py + j / 11 - 5, xx = px + j % 11 - 5;
    if (yy >= 0 && yy < 56 && xx >= 0 && xx < 56) {
      const unsigned short* row = (win < 5) ? rowU : rowV;
      atomicAdd(&wsum[win], bf2f(row[yy * 56 + xx]));
    }
  }
  __syncthreads();
  if (tid == 0) {
    float t = 0.f;
    #pragma unroll
    for (int k = 0; k < 10; ++k) t += wsum[k];
    atomicAdd(acc, t * scale);
  }
}

// standalone sampling kernel (fallback path for stages 1 and 2)
template <int NT>
__global__ __launch_bounds__(NT) void sample5_k(const unsigned short* __restrict__ CS,
    float* __restrict__ acc, uint32_t key0, uint32_t key1, int BC, float scale) {
  __shared__ unsigned kmin[10];
  __shared__ float wsum[10];
  sample5_body<NT>(CS, acc, key0, key1, BC, scale, blockIdx.x, kmin, wsum);
}

// ---------------------------------------------------------------------------
// HALF-pair argmin (phase A): pixels [half*1568,(half+1)*1568) of pair u.
// NO windows, NO acc, NO device atomics/fences (round-9 lesson: mid-kernel
// device fences force cross-XCD L2 invalidation -> 2x HBM traffic, 26% VALU).
// Result: 10 block-local minima -> PLAIN stores to a dedicated global slot;
// the phase-B kernel launch boundary provides the coherence for free.
// Keys embed the global pixel index -> bit-exact split.
// ---------------------------------------------------------------------------
template <int NT>
__device__ void sample5_half_argmin(const unsigned short* __restrict__ CS,
    uint32_t key0, uint32_t key1, int BC, int u, int half,
    unsigned* __restrict__ outk, unsigned* kmin) {
  const int v = u + (BC >> 1);
  const uint32_t sC = (uint32_t)BC * (uint32_t)HW;
  const uint32_t halfn = sC * 2u + (sC >> 1);
  const unsigned short* rowU = CS + (size_t)u * HW;
  const unsigned short* rowV = CS + (size_t)v * HW;
  const int tid = threadIdx.x;
  const int lane = tid & 63;

  if (tid < 10) kmin[tid] = 0xFFFFFFFFu;

  unsigned bk[10];
  #pragma unroll
  for (int k = 0; k < 10; ++k) bk[k] = 0xFFFFFFFFu;

  const uint32_t baseU0 = (uint32_t)u * (uint32_t)HW;
  const uint32_t baseV0 = (uint32_t)v * (uint32_t)HW;
  const int pEnd = (half + 1) * (HW / 2);
  for (int p = half * (HW / 2) + tid; p < pEnd; p += NT) {
    float wu = __builtin_amdgcn_exp2f(bf2f(rowU[p]) * NEG2LOG2E);  // exp(-2c)
    float wv = __builtin_amdgcn_exp2f(bf2f(rowV[p]) * NEG2LOG2E);
    uint32_t eU = baseU0 + (uint32_t)p;
    uint32_t eV = baseV0 + (uint32_t)p;
    uint32_t xa[5] = {eU, eU + sC, eU + 2 * sC, eV, eV + sC};
    uint32_t xb[5] = {eU + halfn, eU + sC + halfn, eU + 2 * sC + halfn,
                      eV + halfn, eV + sC + halfn};
    uint32_t oa[5], ob[5];
    threefry5(key0, key1, xa, xb, oa, ob);
    uint32_t wds[10] = {oa[0], oa[1], oa[2], ob[3], ob[4],   // u s0..s4
                        oa[3], oa[4], ob[0], ob[1], ob[2]};  // v s0..s4
    #pragma unroll
    for (int k = 0; k < 10; ++k) {
      float s = exp_draw(wds[k]) * (k < 5 ? wu : wv);
      unsigned key = (__float_as_uint(s) & 0xFFFFF000u) | (unsigned)p;
      bk[k] = bk[k] < key ? bk[k] : key;
    }
  }

  __syncthreads();  // kmin init visible
  #pragma unroll
  for (int k = 0; k < 10; ++k) {
    unsigned kv = bk[k];
    #pragma unroll
    for (int o = 32; o; o >>= 1) {
      unsigned ov = __shfl_xor(kv, o);
      kv = kv < ov ? kv : ov;
    }
    if (lane == 0) atomicMin(&kmin[k], kv);
  }
  __syncthreads();
  if (tid < 10) outk[tid] = kmin[tid];   // plain store, dedicated slot
}

// ---------------------------------------------------------------------------
// MEGA phase A: 2*nPairs half-blocks + finals on the FIRST 512 blocks, done
// BEFORE their sampling half. Rationale (rounds 6-9): cohorts complete in
// lockstep, so post-pair finals always form an exposed all-memory burst.
// Finals-first on 2 blocks/CU leaves 6 blocks/CU (24 waves) sampling during
// the ~33us final drain, then those blocks join sampling. 6144 half-blocks =
// 3 full-residency cohorts at the measured-efficient 8 blocks/CU; no
// cross-block sync anywhere. Round-10 verdict: 177us @ 90.7% VALUBusy ==
// the sampling VALU floor (160.6us integral). Do not touch.
// Pair list: [0,512) s1 (CS1,A0/A1,BC=1024), [512,1024) s2 (CS2,A2/B0,1024),
//            [1024,3072) s3 (CS3,B1/B2,4096).
// ---------------------------------------------------------------------------
__device__ __forceinline__ void final_chunk(int chunk,
    const unsigned short* __restrict__ Y3, const float* __restrict__ X,
    const float* __restrict__ sc, const float* __restrict__ sh,
    float* __restrict__ out) {
  size_t i = ((size_t)chunk * 256 + threadIdx.x) * 4;
  int c = (int)((i / HW) % 256);
  float a = sc[c], d = sh[c];
  uint2 yd = *(const uint2*)&Y3[i];
  float4 xv = *(const float4*)&X[i];
  float4 r;
  r.x = fmaxf(0.f, fmaf(bf2f((unsigned short)(yd.x & 0xffff)), a, d) + xv.x);
  r.y = fmaxf(0.f, fmaf(bf2f((unsigned short)(yd.x >> 16)),    a, d) + xv.y);
  r.z = fmaxf(0.f, fmaf(bf2f((unsigned short)(yd.y & 0xffff)), a, d) + xv.z);
  r.w = fmaxf(0.f, fmaf(bf2f((unsigned short)(yd.y >> 16)),    a, d) + xv.w);
  *(float4*)&out[i] = r;
}

__global__ __launch_bounds__(256, 8) void mega_argmin_k(
    const unsigned short* __restrict__ CS1, const unsigned short* __restrict__ CS2,
    const unsigned short* __restrict__ CS3,
    const unsigned short* __restrict__ Y3, const float* __restrict__ X,
    const float* __restrict__ sc, const float* __restrict__ sh,
    float* __restrict__ out, unsigned* __restrict__ bkmin,
    uint32_t A0, uint32_t A1, uint32_t A2, uint32_t B0, uint32_t B1, uint32_t B2,
    int pairStart, int finb) {
  __shared__ unsigned kmin[10];
  const int g = blockIdx.x;
  if (g < finb)  // finals FIRST on 2 blocks/CU; sampling continues elsewhere
    for (int cc = g; cc < 12544; cc += finb)
      final_chunk(cc, Y3, X, sc, sh, out);
  const int lp = g >> 1, half = g & 1;
  const int pi = pairStart + lp;
  const unsigned short* CSp; int u; uint32_t k0, k1; int BC;
  if (pi < 512)       { CSp = CS1; u = pi;        k0 = A0; k1 = A1; BC = 1024; }
  else if (pi < 1024) { CSp = CS2; u = pi - 512;  k0 = A2; k1 = B0; BC = 1024; }
  else                { CSp = CS3; u = pi - 1024; k0 = B1; k1 = B2; BC = 4096; }
  sample5_half_argmin<256>(CSp, k0, k1, BC, u, half, bkmin + (size_t)g * 10, kmin);
}

// ---------------------------------------------------------------------------
// MEGA phase B v2: combine half minima + 11x11 window sums, ATOMIC-FREE.
// Round-10 lesson: the old combine's LDS atomicAdd had all 64 lanes of a
// wave hitting the SAME wsum address (idx/121 wave-constant) -> 64-way
// serialization, ~5us/pair, 47us total. v2: one pair per block; wave w owns
// winners {w, w+4, w+8}; 121 window pixels over 64 lanes (<=2 loads each),
// __shfl_xor reduce, one plain LDS store per winner. Result -> plain store
// psum[rp]; the scalar tail sums psum in a final tiny kernel (kernel
// boundary = coherence; no device atomics, no fences anywhere).
// ---------------------------------------------------------------------------
__global__ __launch_bounds__(256) void combine_k(
    const unsigned short* __restrict__ CS1, const unsigned short* __restrict__ CS2,
    const unsigned short* __restrict__ CS3,
    const unsigned* __restrict__ bkmin, float* __restrict__ psum,
    float s64, float s256, int pairStart) {
  __shared__ unsigned kmin[10];
  __shared__ float wsum[10];
  const int tid = threadIdx.x, lane = tid & 63, wv = tid >> 6;
  const int rp = blockIdx.x;
  const int pi = pairStart + rp;
  const unsigned short* rowU; const unsigned short* rowV; float scale;
  if (pi < 512) {
    rowU = CS1 + (size_t)pi * HW; rowV = CS1 + (size_t)(pi + 512) * HW; scale = s64;
  } else if (pi < 1024) {
    int u = pi - 512;
    rowU = CS2 + (size_t)u * HW; rowV = CS2 + (size_t)(u + 512) * HW; scale = s64;
  } else {
    int u = pi - 1024;
    rowU = CS3 + (size_t)u * HW; rowV = CS3 + (size_t)(u + 2048) * HW; scale = s256;
  }
  if (tid < 10) {
    unsigned a = bkmin[(size_t)(2 * rp) * 10 + tid];
    unsigned b = bkmin[(size_t)(2 * rp + 1) * 10 + tid];
    kmin[tid] = a < b ? a : b;
  }
  __syncthreads();
  for (int win = wv; win < 10; win += 4) {   // each winner owned by ONE wave
    int bidx = (int)(kmin[win] & 0xFFFu);
    int py = bidx / 56, px = bidx % 56;
    const unsigned short* row = (win < 5) ? rowU : rowV;
    float s = 0.f;
    for (int j = lane; j < 121; j += 64) {
      int yy = py + j / 11 - 5, xx = px + j % 11 - 5;
      if (yy >= 0 && yy < 56 && xx >= 0 && xx < 56)
        s += bf2f(row[yy * 56 + xx]);
    }
    #pragma unroll
    for (int o = 32; o; o >>= 1) s += __shfl_xor(s, o);
    if (lane == 0) wsum[win] = s;            // sole writer: no race
  }
  __syncthreads();
  if (tid == 0) {
    float t = 0.f;
    #pragma unroll
    for (int k = 0; k < 10; ++k) t += wsum[k];
    psum[rp] = t * scale;                    // plain store
  }
}

// scalar tail: out[12845056] = sum(psum[0..n)) + acc (fallback s1/s2 residue)
__global__ __launch_bounds__(256) void acc_write_k(const float* __restrict__ psum,
    const float* __restrict__ acc, float* __restrict__ out, int n) {
  __shared__ float W[4];
  const int tid = threadIdx.x, lane = tid & 63, wv = tid >> 6;
  float s = 0.f;
  for (int i = tid; i < n; i += 256) s += psum[i];
  #pragma unroll
  for (int o = 32; o; o >>= 1) s += __shfl_xor(s, o);
  if (lane == 0) W[wv] = s;
  __syncthreads();
  if (tid == 0) out[12845056] = W[0] + W[1] + W[2] + W[3] + acc[0];
}

// ---------------------------------------------------------------------------
// weight prep: invwn[384] (1/(||w||+eps)) + bf16 weight conversion.
// ---------------------------------------------------------------------------
__global__ void wprep_k(const float* __restrict__ w1, const float* __restrict__ w2,
                        const float* __restrict__ w3, float* __restrict__ invwn,
                        unsigned short* __restrict__ W1b, unsigned short* __restrict__ W2tb,
                        unsigned short* __restrict__ W3b) {
  int i = blockIdx.x * 256 + threadIdx.x;
  if (i < 16384) {
    W1b[i] = f2bf(w1[i]);
  } else if (i < 53248) {
    int o = i - 16384;
    int co = o / 576, r = o % 576, tap = r >> 6, ci = r & 63;
    W2tb[o] = f2bf(w2[co * 576 + ci * 9 + tap]);
  } else if (i < 69632) {
    int o = i - 53248;
    W3b[o] = f2bf(w3[o]);
  } else {
    int t = i - 69632;
    if (t < 64) {
      float s = 0.f;
      for (int k = 0; k < 256; k++) { float v = w1[t * 256 + k]; s = fmaf(v, v, s); }
      invwn[t] = 1.0f / (sqrtf(s) + 1e-6f);
    } else if (t < 128) {
      int c = t - 64; float s = 0.f;
      for (int k = 0; k < 576; k++) { float v = w2[c * 576 + k]; s = fmaf(v, v, s); }
      invwn[t] = 1.0f / (sqrtf(s) + 1e-6f);
    } else if (t < 384) {
      int c = t - 128; float s = 0.f;
      for (int k = 0; k < 64; k++) { float v = w3[c * 64 + k]; s = fmaf(v, v, s); }
      invwn[t] = 1.0f / (sqrtf(s) + 1e-6f);
    }
  }
}

// ---------------------------------------------------------------------------
// BN finalize from per-block partials, channel-major [co][nblk].
// ---------------------------------------------------------------------------
__global__ __launch_bounds__(256) void bn_fin(const float* __restrict__ Sp,
    const float* __restrict__ Qp, const float* __restrict__ g,
    const float* __restrict__ b, float* __restrict__ sc, float* __restrict__ sh,
    int nblk) {
  const int c = blockIdx.x, tid = threadIdx.x;
  const float* rs = Sp + (size_t)c * nblk;
  const float* rq = Qp + (size_t)c * nblk;
  float s = 0.f, q = 0.f;
  for (int i = tid; i < nblk; i += 256) { s += rs[i]; q += rq[i]; }
  #pragma unroll
  for (int o = 32; o; o >>= 1) { s += __shfl_xor(s, o); q += __shfl_xor(q, o); }
  __shared__ float S[4], Q[4];
  int lane = tid & 63, wave = tid >> 6;
  if (lane == 0) { S[wave] = s; Q[wave] = q; }
  __syncthreads();
  if (tid == 0) {
    float st = S[0] + S[1] + S[2] + S[3];
    float qt = Q[0] + Q[1] + Q[2] + Q[3];
    float mean = st * (1.0f / (float)NPIX);
    float var = qt * (1.0f / (float)NPIX) - mean * mean;  // biased, jnp.var
    float sv = g[c] / sqrtf(var + 1e-5f);
    sc[c] = sv; sh[c] = b[c] - mean * sv;
  }
}

// ---------------------------------------------------------------------------
// conv1: 1x1 256->64 MFMA. Block = 64px x 64co, grid (49,16).
// ---------------------------------------------------------------------------
__global__ __launch_bounds__(256) void conv1_mfma(
    const float* __restrict__ X, const unsigned short* __restrict__ Wb,
    const float* __restrict__ invwn, unsigned short* __restrict__ Y1,
    unsigned short* __restrict__ CS, float* __restrict__ Sp, float* __restrict__ Qp) {
#define ST1 264
#define NB1 784
  __shared__ __align__(16) unsigned short bq[64 * ST1];
  __shared__ float sqp[4][64];
  __shared__ float ixn[64];
  const int p0 = blockIdx.x * 64, b = blockIdx.y;
  const int bid = b * 49 + blockIdx.x;
  const int tid = threadIdx.x;
  const int lane = tid & 63, wave = tid >> 6;
  const int m = lane & 15, quad = lane >> 4;
  const int co0 = wave * 16;
  const float* Xb = X + (size_t)b * 256 * HW + p0;

  bf16x8 afr[8];
  const unsigned short* wrow = Wb + (co0 + m) * 256 + quad * 8;
  #pragma unroll
  for (int k = 0; k < 8; ++k) afr[k] = *(const bf16x8*)(wrow + k * 32);

  {
    const int px = tid & 63, rg = tid >> 6;
    float sq = 0.f;
    #pragma unroll
    for (int it = 0; it < 16; ++it) {
      int ci = rg * 64 + it * 4;
      float v0 = Xb[(size_t)(ci + 0) * HW + px];
      float v1 = Xb[(size_t)(ci + 1) * HW + px];
      float v2 = Xb[(size_t)(ci + 2) * HW + px];
      float v3 = Xb[(size_t)(ci + 3) * HW + px];
      sq += v0 * v0 + v1 * v1 + v2 * v2 + v3 * v3;
      *(uint2*)&bq[px * ST1 + ci] = make_uint2(pk2(v0, v1), pk2(v2, v3));
    }
    sqp[rg][px] = sq;
  }
  __syncthreads();
  if (tid < 64)
    ixn[tid] = 1.0f / (sqrtf(sqp[0][tid] + sqp[1][tid] + sqp[2][tid] + sqp[3][tid]) + 1e-6f);
  __syncthreads();

  f32x4 acc[4];
  #pragma unroll
  for (int nt = 0; nt < 4; ++nt) acc[nt] = (f32x4)0.f;
  #pragma unroll
  for (int nt = 0; nt < 4; ++nt) {
    const unsigned short* brow = &bq[(nt * 16 + m) * ST1 + quad * 8];
    #pragma unroll
    for (int k = 0; k < 8; ++k) {
      bf16x8 bfrag = *(const bf16x8*)(brow + k * 32);
      acc[nt] = MFMA16(afr[k], bfrag, acc[nt]);
    }
  }

  float s[4] = {0, 0, 0, 0}, q[4] = {0, 0, 0, 0};
  #pragma unroll
  for (int nt = 0; nt < 4; ++nt) {
    int px = nt * 16 + m;
    size_t bp = (size_t)b * HW + p0 + px;
    float ix = ixn[px];
    *(uint2*)&Y1[bp * 64 + co0 + quad * 4] =
        make_uint2(pk2(acc[nt][0], acc[nt][1]), pk2(acc[nt][2], acc[nt][3]));
    #pragma unroll
    for (int r = 0; r < 4; ++r) {
      int co = co0 + quad * 4 + r;
      float v = acc[nt][r];
      CS[((size_t)b * 64 + co) * HW + p0 + px] = f2bf(v * invwn[co] * ix);
      s[r] += v; q[r] = fmaf(v, v, q[r]);
    }
  }
  #pragma unroll
  for (int r = 0; r < 4; ++r) {
    float ss = s[r], qq = q[r];
    #pragma unroll
    for (int o = 8; o; o >>= 1) { ss += __shfl_xor(ss, o); qq += __shfl_xor(qq, o); }
    if (m == 0) {
      int co = co0 + quad * 4 + r;
      Sp[(size_t)co * NB1 + bid] = ss; Qp[(size_t)co * NB1 + bid] = qq;
    }
  }
#undef NB1
#undef ST1
}

// ---------------------------------------------------------------------------
// conv2: 3x3 64->64 pad1, implicit-GEMM MFMA. grid (56,16). CS bf16.
// FUSED x_norm: ts tile IS relu(bn1(y1)) (zero-padded) == exactly what
// part(pixel) = sum_ci t1^2 needs for rows h-1..h+1; spart + 3x3 box in
// the epilogue.
// ---------------------------------------------------------------------------
__global__ __launch_bounds__(256) void conv2_mfma(
    const unsigned short* __restrict__ Y1, const unsigned short* __restrict__ W2tb,
    const float* __restrict__ invwn,
    const float* __restrict__ sc1, const float* __restrict__ sh1,
    unsigned short* __restrict__ Y2, unsigned short* __restrict__ CS,
    float* __restrict__ Sp, float* __restrict__ Qp) {
#define STW 72
#define NB2 896
  __shared__ __align__(16) unsigned short ts[3 * 66 * STW];
  __shared__ float scl[64], shl[64];
  __shared__ float spart[3 * 56];
  const int h = blockIdx.x, b = blockIdx.y;
  const int bid = b * 56 + h;
  const int tid = threadIdx.x;
  const int lane = tid & 63, wave = tid >> 6;
  const int m = lane & 15, quad = lane >> 4;
  const int co0 = wave * 16;
  if (tid < 64) { scl[tid] = sc1[tid]; shl[tid] = sh1[tid]; }

  bf16x8 afr[18];
  #pragma unroll
  for (int ks = 0; ks < 18; ++ks)
    afr[ks] = *(const bf16x8*)(W2tb + (co0 + m) * 576 + ks * 32 + quad * 8);
  __syncthreads();

  for (int l = tid; l < 6336; l += 256) {  // 3 rows x 66 cols x 32 ci-pairs
    int cp = l & 31, cc = (l >> 5) % 66, dy = l / 2112;
    int yy = h - 1 + dy, xx = cc - 1;
    unsigned pkv = 0u;
    if (yy >= 0 && yy < 56 && xx >= 0 && xx < 56) {
      unsigned d = *(const unsigned*)&Y1[((size_t)b * HW + yy * 56 + xx) * 64 + cp * 2];
      float v0 = bf2f((unsigned short)(d & 0xffff));
      float v1 = bf2f((unsigned short)(d >> 16));
      v0 = fmaxf(0.f, fmaf(v0, scl[cp * 2], shl[cp * 2]));
      v1 = fmaxf(0.f, fmaf(v1, scl[cp * 2 + 1], shl[cp * 2 + 1]));
      pkv = pk2(v0, v1);
    }
    *(unsigned*)&ts[(dy * 66 + cc) * STW + cp * 2] = pkv;
  }
  __syncthreads();

  // spart[dy][x] = sum_ci ts[dy][x+1][ci]^2
  if (tid < 168) {
    int dy = tid / 56, x = tid - dy * 56;
    const unsigned* row = (const unsigned*)&ts[(dy * 66 + x + 1) * STW];
    float s = 0.f;
    #pragma unroll
    for (int j = 0; j < 32; ++j) {
      unsigned d = row[j];
      float v0 = bf2f((unsigned short)(d & 0xffff));
      float v1 = bf2f((unsigned short)(d >> 16));
      s = fmaf(v0, v0, s); s = fmaf(v1, v1, s);
    }
    spart[tid] = s;
  }
  __syncthreads();

  f32x4 acc[4];
  #pragma unroll
  for (int nt = 0; nt < 4; ++nt) acc[nt] = (f32x4)0.f;
  #pragma unroll
  for (int nt = 0; nt < 4; ++nt) {
    #pragma unroll
    for (int ks = 0; ks < 18; ++ks) {
      int tap = ks >> 1, half = ks & 1;
      int dy = tap / 3, dx = tap % 3;
      bf16x8 bfrag = *(const bf16x8*)&ts[(dy * 66 + nt * 16 + m + dx) * STW + half * 32 + quad * 8];
      acc[nt] = MFMA16(afr[ks], bfrag, acc[nt]);
    }
  }

  float s[4] = {0, 0, 0, 0}, q[4] = {0, 0, 0, 0};
  #pragma unroll
  for (int nt = 0; nt < 4; ++nt) {
    int px = nt * 16 + m;
    bool valid = px < 56;
    int pix = h * 56 + px;
    if (valid) {
      float tot = 0.f;
      #pragma unroll
      for (int dy = 0; dy < 3; ++dy) {
        #pragma unroll
        for (int dx = -1; dx <= 1; ++dx) {
          int xx = px + dx;
          if (xx >= 0 && xx < 56) tot += spart[dy * 56 + xx];
        }
      }
      float ix = 1.0f / (sqrtf(tot) + 1e-6f);
      size_t bp = (size_t)b * HW + pix;
      *(uint2*)&Y2[bp * 64 + co0 + quad * 4] =
          make_uint2(pk2(acc[nt][0], acc[nt][1]), pk2(acc[nt][2], acc[nt][3]));
      #pragma unroll
      for (int r = 0; r < 4; ++r) {
        int co = co0 + quad * 4 + r;
        CS[((size_t)b * 64 + co) * HW + pix] = f2bf(acc[nt][r] * invwn[co] * ix);
      }
    }
    #pragma unroll
    for (int r = 0; r < 4; ++r) {
      float v = valid ? acc[nt][r] : 0.f;
      s[r] += v; q[r] = fmaf(v, v, q[r]);
    }
  }
  #pragma unroll
  for (int r = 0; r < 4; ++r) {
    float ss = s[r], qq = q[r];
    #pragma unroll
    for (int o = 8; o; o >>= 1) { ss += __shfl_xor(ss, o); qq += __shfl_xor(qq, o); }
    if (m == 0) {
      int co = co0 + quad * 4 + r;
      Sp[(size_t)co * NB2 + bid] = ss; Qp[(size_t)co * NB2 + bid] = qq;
    }
  }
#undef NB2
#undef STW
}

// ---------------------------------------------------------------------------
// conv3: 1x1 64->256 MFMA. grid (49,16). Outputs y3 bf16 + cos3 bf16.
// ---------------------------------------------------------------------------
__global__ __launch_bounds__(256) void conv3_mfma(
    const unsigned short* __restrict__ Y2, const unsigned short* __restrict__ W3b,
    const float* __restrict__ invwn,
    const float* __restrict__ sc2, const float* __restrict__ sh2,
    unsigned short* __restrict__ Y3, unsigned short* __restrict__ CS,
    float* __restrict__ Sp, float* __restrict__ Qp) {
#define ST3 72
#define NB3 784
  __shared__ __align__(16) unsigned short bq[64 * ST3];
  __shared__ float scl[64], shl[64], sqp[4][64], ixn[64];
  const int p0 = blockIdx.x * 64, b = blockIdx.y;
  const int bid = b * 49 + blockIdx.x;
  const int tid = threadIdx.x;
  const int lane = tid & 63, wave = tid >> 6;
  const int m = lane & 15, quad = lane >> 4;
  const int co0 = wave * 64;
  if (tid < 64) { scl[tid] = sc2[tid]; shl[tid] = sh2[tid]; }

  bf16x8 afr[4][2];
  #pragma unroll
  for (int mt = 0; mt < 4; ++mt)
    #pragma unroll
    for (int k = 0; k < 2; ++k)
      afr[mt][k] = *(const bf16x8*)(W3b + (co0 + mt * 16 + m) * 64 + k * 32 + quad * 8);
  __syncthreads();

  {
    const int cp = tid & 31, pxg = tid >> 5;
    #pragma unroll
    for (int it = 0; it < 8; ++it) {
      int px = pxg * 8 + it;
      unsigned d = *(const unsigned*)&Y2[((size_t)b * HW + p0 + px) * 64 + cp * 2];
      float v0 = bf2f((unsigned short)(d & 0xffff));
      float v1 = bf2f((unsigned short)(d >> 16));
      v0 = fmaxf(0.f, fmaf(v0, scl[cp * 2], shl[cp * 2]));
      v1 = fmaxf(0.f, fmaf(v1, scl[cp * 2 + 1], shl[cp * 2 + 1]));
      *(unsigned*)&bq[px * ST3 + cp * 2] = pk2(v0, v1);
    }
  }
  __syncthreads();
  {
    const int px = tid & 63, hh = tid >> 6;
    const unsigned short* row = &bq[px * ST3 + hh * 16];
    float sq = 0.f;
    #pragma unroll
    for (int e = 0; e < 16; ++e) { float v = bf2f(row[e]); sq = fmaf(v, v, sq); }
    sqp[hh][px] = sq;
  }
  __syncthreads();
  if (tid < 64)
    ixn[tid] = 1.0f / (sqrtf(sqp[0][tid] + sqp[1][tid] + sqp[2][tid] + sqp[3][tid]) + 1e-6f);
  __syncthreads();

  f32x4 acc[4][4];
  #pragma unroll
  for (int mt = 0; mt < 4; ++mt)
    #pragma unroll
    for (int nt = 0; nt < 4; ++nt) acc[mt][nt] = (f32x4)0.f;
  #pragma unroll
  for (int nt = 0; nt < 4; ++nt) {
    const unsigned short* brow = &bq[(nt * 16 + m) * ST3 + quad * 8];
    bf16x8 b0 = *(const bf16x8*)(brow);
    bf16x8 b1 = *(const bf16x8*)(brow + 32);
    #pragma unroll
    for (int mt = 0; mt < 4; ++mt) {
      acc[mt][nt] = MFMA16(afr[mt][0], b0, acc[mt][nt]);
      acc[mt][nt] = MFMA16(afr[mt][1], b1, acc[mt][nt]);
    }
  }

  #pragma unroll
  for (int mt = 0; mt < 4; ++mt) {
    float s[4] = {0, 0, 0, 0}, q[4] = {0, 0, 0, 0};
    #pragma unroll
    for (int nt = 0; nt < 4; ++nt) {
      int px = nt * 16 + m;
      float ix = ixn[px];
      #pragma unroll
      for (int r = 0; r < 4; ++r) {
        int co = co0 + mt * 16 + quad * 4 + r;
        float v = acc[mt][nt][r];
        size_t off = ((size_t)b * 256 + co) * HW + p0 + px;
        Y3[off] = f2bf(v);
        CS[off] = f2bf(v * invwn[co] * ix);
        s[r] += v; q[r] = fmaf(v, v, q[r]);
      }
    }
    #pragma unroll
    for (int r = 0; r < 4; ++r) {
      float ss = s[r], qq = q[r];
      #pragma unroll
      for (int o = 8; o; o >>= 1) { ss += __shfl_xor(ss, o); qq += __shfl_xor(qq, o); }
      if (m == 0) {
        int co = co0 + mt * 16 + quad * 4 + r;
        Sp[(size_t)co * NB3 + bid] = ss; Qp[(size_t)co * NB3 + bid] = qq;
      }
    }
  }
#undef NB3
#undef ST3
}

// ---------------------------------------------------------------------------
extern "C" void kernel_launch(void* const* d_in, const int* in_sizes, int n_in,
                              void* d_out, int out_size, void* d_ws, size_t ws_size,
                              hipStream_t stream) {
  (void)in_sizes; (void)n_in; (void)out_size;
  const float* x  = (const float*)d_in[0];
  const float* w1 = (const float*)d_in[1];
  const float* w2 = (const float*)d_in[2];
  const float* w3 = (const float*)d_in[3];
  const float* g1 = (const float*)d_in[4];
  const float* b1 = (const float*)d_in[5];
  const float* g2 = (const float*)d_in[6];
  const float* b2 = (const float*)d_in[7];
  const float* g3 = (const float*)d_in[8];
  const float* b3 = (const float*)d_in[9];
  float* out = (float*)d_out;
  float* ws = (float*)d_ws;

  // workspace layout (float units; bf16 buffers use elems/2 float units)
  size_t o = 0;
  unsigned short* y3b  = (unsigned short*)(ws + o); o += 6422528;  // 12845056 bf16
  unsigned short* cos3 = (unsigned short*)(ws + o); o += 6422528;  // 12845056 bf16
  unsigned short* CSb  = (unsigned short*)(ws + o); o += 1605632;  // 3211264 bf16
  unsigned short* y1b  = (unsigned short*)(ws + o); o += 1605632;  // 3211264 bf16
  unsigned short* y2b  = (unsigned short*)(ws + o); o += 1605632;  // 3211264 bf16
  unsigned short* W1b  = (unsigned short*)(ws + o); o += 8192;     // 16384 bf16
  unsigned short* W2tb = (unsigned short*)(ws + o); o += 18432;    // 36864 bf16
  unsigned short* W3b  = (unsigned short*)(ws + o); o += 8192;     // 16384 bf16
  float* invwn = ws + o; o += 384;
  float* Sp1 = ws + o; o += 64 * 784;   float* Qp1 = ws + o; o += 64 * 784;
  float* Sp2 = ws + o; o += 64 * 896;   float* Qp2 = ws + o; o += 64 * 896;
  float* Sp3 = ws + o; o += 256 * 784;  float* Qp3 = ws + o; o += 256 * 784;
  float* acc = ws + o; o += 1;          // fallback s1/s2 residue (else 0)
  unsigned* bkmin = (unsigned*)(ws + o); o += 61440;  // 6144 blocks x 10 keys
  float* psum = ws + o; o += 3072;      // per-pair window sums (plain stores)
  float* sc1 = ws + o; o += 64;  float* sh1 = ws + o; o += 64;
  float* sc2 = ws + o; o += 64;  float* sh2 = ws + o; o += 64;
  float* sc3 = ws + o; o += 256; float* sh3 = ws + o; o += 256;

  // Separate conv2-cosine buffer so stage-1/2 sampling can be deferred into
  // the mega kernels (CSb must survive conv2). Guarded by ws_size.
  const bool big = ws_size >= (o + 1605632) * sizeof(float);
  unsigned short* CS2b = big ? (unsigned short*)(ws + o) : CSb;

  hipMemsetAsync(acc, 0, sizeof(float), stream);

  // JAX: k0,k1,k2 = split(key(42), 3); (Ai,Bi) = threefry2x32((0,42),(i,i+3))
  uint32_t A0, B0, A1, B1, A2, B2;
  threefry2x32(0u, 42u, 0u, 3u, A0, B0);
  threefry2x32(0u, 42u, 1u, 4u, A1, B1);
  threefry2x32(0u, 42u, 2u, 5u, A2, B2);

  const float scale64  = 1.0f / (121.0f * 5.0f * 1024.0f);
  const float scale256 = 1.0f / (121.0f * 5.0f * 4096.0f);

  wprep_k<<<274, 256, 0, stream>>>(w1, w2, w3, invwn, W1b, W2tb, W3b);

  // conv pipeline (serial deps: conv1 -> bn1 -> conv2 -> bn2 -> conv3 -> bn3)
  conv1_mfma<<<dim3(49, 16), 256, 0, stream>>>(x, W1b, invwn, y1b, CSb, Sp1, Qp1);
  bn_fin<<<64, 256, 0, stream>>>(Sp1, Qp1, g1, b1, sc1, sh1, 784);
  if (!big)  // fallback: must sample CSb before conv2 overwrites it
    sample5_k<512><<<512, 512, 0, stream>>>(CSb, acc, A0, A1, 1024, scale64);
  conv2_mfma<<<dim3(56, 16), 256, 0, stream>>>(
      y1b, W2tb, invwn + 64, sc1, sh1, y2b, CS2b, Sp2, Qp2);
  bn_fin<<<64, 256, 0, stream>>>(Sp2, Qp2, g2, b2, sc2, sh2, 896);
  if (!big)
    sample5_k<512><<<512, 512, 0, stream>>>(CS2b, acc, A2, B0, 1024, scale64);
  conv3_mfma<<<dim3(49, 16), 256, 0, stream>>>(
      y2b, W3b, invwn + 128, sc2, sh2, y3b, cos3, Sp3, Qp3);
  bn_fin<<<256, 256, 0, stream>>>(Sp3, Qp3, g3, b3, sc3, sh3, 784);

  // Phase A: half-pair argmin (plain-store results) + finals-first on 512
  // blocks. Phase B: atomic-free combine (1 pair/block). Scalar tail kernel.
  if (big) {
    mega_argmin_k<<<6144, 256, 0, stream>>>(
        CSb, CS2b, cos3, y3b, x, sc3, sh3, out, bkmin,
        A0, A1, A2, B0, B1, B2, /*pairStart=*/0, /*finb=*/512);
    combine_k<<<3072, 256, 0, stream>>>(
        CSb, CS2b, cos3, bkmin, psum, scale64, scale256, /*pairStart=*/0);
    acc_write_k<<<1, 256, 0, stream>>>(psum, acc, out, 3072);
  } else {
    mega_argmin_k<<<4096, 256, 0, stream>>>(
        CSb, CS2b, cos3, y3b, x, sc3, sh3, out, bkmin,
        A0, A1, A2, B0, B1, B2, /*pairStart=*/1024, /*finb=*/512);
    combine_k<<<2048, 256, 0, stream>>>(
        CSb, CS2b, cos3, bkmin, psum, scale64, scale256, /*pairStart=*/1024);
    acc_write_k<<<1, 256, 0, stream>>>(psum, acc, out, 2048);
  }
}